// Round 1
// baseline (159.847 us; speedup 1.0000x reference)
//
#include <hip/hip_runtime.h>
#include <hip/hip_bf16.h>

// ---------------------------------------------------------------------------
// Sliding-window attention (B=4,S=2048,D=1024,H=16,HD=64,W=256) on gfx950.
// Pipeline: cvt(f32->bf16) -> GEMM(QKV, 256^2 8-phase) -> RoPE+reshape
//           (+permuted V^T) -> flash window attention -> GEMM(O-proj, 128^2).
// ---------------------------------------------------------------------------

typedef __bf16 bf16_t;
typedef __attribute__((ext_vector_type(8))) __bf16 bf16x8;
typedef __attribute__((ext_vector_type(4))) __bf16 bf16x4;
typedef __attribute__((ext_vector_type(4))) float f32x4;

#define MFMA16(a, b, c) __builtin_amdgcn_mfma_f32_16x16x32_bf16((a), (b), (c), 0, 0, 0)

// async global->LDS, 16 bytes per lane. LDS dest is wave-uniform base + lane*16.
__device__ __forceinline__ void async16(const void* g, void* l) {
    __builtin_amdgcn_global_load_lds(
        (const __attribute__((address_space(1))) unsigned int*)g,
        (__attribute__((address_space(3))) unsigned int*)l, 16, 0, 0);
}

#define BAR() do { asm volatile("" ::: "memory"); __builtin_amdgcn_s_barrier(); \
                   asm volatile("" ::: "memory"); } while (0)
#define VMC(N) asm volatile("s_waitcnt vmcnt(" #N ")" ::: "memory")

// ---------------------------------------------------------------------------
// f32 -> bf16 convert, 8 elems/thread
// ---------------------------------------------------------------------------
__global__ __launch_bounds__(256) void cvt_kernel(const float* __restrict__ s,
                                                  bf16_t* __restrict__ d, int n) {
    int i = (blockIdx.x * 256 + threadIdx.x) * 8;
    if (i >= n) return;
    float4 a = *(const float4*)(s + i);
    float4 b = *(const float4*)(s + i + 4);
    bf16x8 o;
    o[0] = (bf16_t)a.x; o[1] = (bf16_t)a.y; o[2] = (bf16_t)a.z; o[3] = (bf16_t)a.w;
    o[4] = (bf16_t)b.x; o[5] = (bf16_t)b.y; o[6] = (bf16_t)b.z; o[7] = (bf16_t)b.w;
    *(bf16x8*)(d + i) = o;
}

// ---------------------------------------------------------------------------
// 256x256 8-phase GEMM: C[M][N] = A[M][K] @ Bw[N][K]^T  (bf16 in, f32 acc).
// 512 threads = 8 waves (2M x 4N), per-wave C = 128x64. BK=64, double-buffered
// LDS (128 KiB), st_16x32 XOR swizzle, counted vmcnt(4) at phases 4/8 only.
//
// Per K-tile (4 phases), quadrants (mh,nh) = (0,0),(0,1),(1,0),(1,1):
//   p1 reads A-mh0(8 ds) + B-nh0(4 ds); p2 reads B-nh1(4); p3 reads A-mh1(8);
//   p4 reads nothing (all regs live).  LDS last-touch: Ah0@p1, Bh0@p1,
//   Bh1@p2, Ah1@p3.
// Stage slots (one half-tile = 2 gload_lds/thread per phase), tiles T=2i,T+1:
//   p1:A0(T+1) p2:A1(T+1) p3:B0(T+2) p4:B1(T+2) p5:A0(T+2) p6:A1(T+2)
//   p7:B0(T+3) p8:B1(T+3)
// Every stage of half H at phase k: H's last ds_read completed (MFMA data-dep
// drains lgkm before that phase's MFMA) before a barrier preceding k's issue.
// vmcnt(4)+barrier at p4 drains {A(T+1) from p1/p2, B(T+1) from prev p7/p8}
// -> tile T+1 certified for p5-p8. vmcnt(4) at p8 certifies T+2 for next p1.
// ---------------------------------------------------------------------------
template <typename OUT>
__global__ __launch_bounds__(512, 2) void gemm256(const bf16_t* __restrict__ A,
                                                  const bf16_t* __restrict__ Bw,
                                                  OUT* __restrict__ C,
                                                  int M, int N, int K) {
    __shared__ __attribute__((aligned(16))) bf16_t As[32768];   // 2 buf x 2 half x 128x64
    __shared__ __attribute__((aligned(16))) bf16_t Bs[32768];
    const int tid = threadIdx.x;
    const int l = tid & 63, w = tid >> 6;
    const int lr = l & 15, lg = l >> 4;
    const int wr = w >> 2, wc = w & 3;

    const int nwg = gridDim.x * gridDim.y;
    const int flat = blockIdx.y * gridDim.x + blockIdx.x;
    const int swz = (flat & 7) * (nwg >> 3) + (flat >> 3);
    const int bx = swz % gridDim.x, by = swz / gridDim.x;
    const long m0 = (long)by * 256, n0 = (long)bx * 256;
    const int NT = K >> 6;       // number of 64-wide K tiles (assumed even, >=4)
    const int NI = NT >> 1;      // iterations (2 tiles each)

    // staging decode: wave w, load i fills subtile st=i*8+w (1 KiB) of a half.
    // LDS byte p (linear dest) -> unswizzle -> (row r, col c) of 128x64 half.
    int rS[2], cS[2];
#pragma unroll
    for (int i = 0; i < 2; ++i) {
        const int p  = i * 8192 + w * 1024 + l * 16;
        const int pp = p ^ (((p >> 9) & 1) << 5);
        const int st = pp >> 10;
        rS[i] = (st >> 1) * 16 + ((pp >> 6) & 15);
        cS[i] = (st & 1) * 32 + ((pp >> 4) & 3) * 8;
    }
    const bf16_t* aSrc0 = A  + (m0 + rS[0]) * K + cS[0];
    const bf16_t* aSrc1 = A  + (m0 + rS[1]) * K + cS[1];
    const bf16_t* bSrc0 = Bw + (n0 + rS[0]) * K + cS[0];
    const bf16_t* bSrc1 = Bw + (n0 + rS[1]) * K + cS[1];
    const long hK = 128L * K;    // half-tile global row stride (elements)

    auto stageA = [&](int b, int h, int t) {
        char* d = (char*)As + b * 32768 + h * 16384 + w * 1024;
        const long o = (long)h * hK + (long)t * 64;
        async16(aSrc0 + o, d);
        async16(aSrc1 + o, d + 8192);
    };
    auto stageB = [&](int b, int h, int t) {
        char* d = (char*)Bs + b * 32768 + h * 16384 + w * 1024;
        const long o = (long)h * hK + (long)t * 64;
        async16(bSrc0 + o, d);
        async16(bSrc1 + o, d + 8192);
    };

    f32x4 acc[8][4] = {};
    bf16x8 af[4][2], bh0[2][2], bh1[2][2];
    const int swd = (lr & 8) << 2;   // ds_read swizzle: bit5 ^= bit9 (= lr bit3)

    auto loadA = [&](int b, int mh) {
#pragma unroll
        for (int i = 0; i < 4; ++i)
#pragma unroll
            for (int ks = 0; ks < 2; ++ks) {
                const int off = ((mh * 4 + i) * 2 + ks) * 1024 + lr * 64 + lg * 16;
                af[i][ks] = *(const bf16x8*)((const char*)As + b * 32768 +
                                             wr * 16384 + (off ^ swd));
            }
    };
    auto loadB = [&](int b, int nh, bf16x8 (&dst)[2][2]) {
#pragma unroll
        for (int j = 0; j < 2; ++j)
#pragma unroll
            for (int ks = 0; ks < 2; ++ks) {
                const int off = (((wc & 1) * 4 + nh * 2 + j) * 2 + ks) * 1024 +
                                lr * 64 + lg * 16;
                dst[j][ks] = *(const bf16x8*)((const char*)Bs + b * 32768 +
                                              (wc >> 1) * 16384 + (off ^ swd));
            }
    };

#define QMM(MH, NH, BF) do {                                                        \
    __builtin_amdgcn_s_setprio(1);                                                  \
    _Pragma("unroll")                                                               \
    for (int qi = 0; qi < 4; ++qi) {                                                \
        acc[(MH)*4+qi][(NH)*2]   = MFMA16(af[qi][0], (BF)[0][0], acc[(MH)*4+qi][(NH)*2]);   \
        acc[(MH)*4+qi][(NH)*2]   = MFMA16(af[qi][1], (BF)[0][1], acc[(MH)*4+qi][(NH)*2]);   \
        acc[(MH)*4+qi][(NH)*2+1] = MFMA16(af[qi][0], (BF)[1][0], acc[(MH)*4+qi][(NH)*2+1]); \
        acc[(MH)*4+qi][(NH)*2+1] = MFMA16(af[qi][1], (BF)[1][1], acc[(MH)*4+qi][(NH)*2+1]); \
    }                                                                               \
    __builtin_amdgcn_s_setprio(0);                                                  \
} while (0)

    // ---- prologue: tile0 fully + tile1's B halves; certify tile0 ----
    stageB(0, 0, 0); stageB(0, 1, 0); stageA(0, 0, 0); stageA(0, 1, 0);
    stageB(1, 0, 1); stageB(1, 1, 1);
    VMC(4);          // 12 outstanding -> drain tile0's 8, keep tile1-B's 4
    BAR();

#pragma unroll 1
    for (int it = 0; it < NI - 1; ++it) {
        const int T = it * 2;
        // P1
        loadA(0, 0); loadB(0, 0, bh0); stageA(1, 0, T + 1);
        BAR(); QMM(0, 0, bh0); BAR();
        // P2
        loadB(0, 1, bh1); stageA(1, 1, T + 1);
        BAR(); QMM(0, 1, bh1); BAR();
        // P3
        loadA(0, 1); stageB(0, 0, T + 2);
        BAR(); QMM(1, 0, bh0); BAR();
        // P4  (certify tile T+1: drain to the p3/p4 stages = 4 loads)
        stageB(0, 1, T + 2);
        BAR(); QMM(1, 1, bh1); VMC(4); BAR();
        // P5
        loadA(1, 0); loadB(1, 0, bh0); stageA(0, 0, T + 2);
        BAR(); QMM(0, 0, bh0); BAR();
        // P6
        loadB(1, 1, bh1); stageA(0, 1, T + 2);
        BAR(); QMM(0, 1, bh1); BAR();
        // P7
        loadA(1, 1); stageB(1, 0, T + 3);
        BAR(); QMM(1, 0, bh0); BAR();
        // P8  (certify tile T+2: drain to the p7/p8 stages = 4 loads)
        stageB(1, 1, T + 3);
        BAR(); QMM(1, 1, bh1); VMC(4); BAR();
    }

    // ---- final iteration (tiles NT-2, NT-1): stage only A(NT-1), then drain ----
    {
        const int T = NT - 2;
        loadA(0, 0); loadB(0, 0, bh0); stageA(1, 0, T + 1);
        BAR(); QMM(0, 0, bh0); BAR();
        loadB(0, 1, bh1); stageA(1, 1, T + 1);
        BAR(); QMM(0, 1, bh1); BAR();
        loadA(0, 1);
        BAR(); QMM(1, 0, bh0); QMM(1, 1, bh1);
        VMC(0); BAR();
        // last tile: no LDS writers remain -> no barriers needed
        loadA(1, 0); loadB(1, 0, bh0);
        QMM(0, 0, bh0);
        loadB(1, 1, bh1);
        QMM(0, 1, bh1);
        loadA(1, 1);
        QMM(1, 0, bh0);
        QMM(1, 1, bh1);
    }
#undef QMM

    // ---- epilogue: fragment row = lg*4+j, col = lr ----
#pragma unroll
    for (int mi = 0; mi < 8; ++mi)
#pragma unroll
        for (int ni = 0; ni < 4; ++ni)
#pragma unroll
            for (int j = 0; j < 4; ++j) {
                long r = m0 + wr * 128 + mi * 16 + lg * 4 + j;
                long c = n0 + wc * 64 + ni * 16 + lr;
                C[r * (long)N + c] = (OUT)acc[mi][ni][j];
            }
}

// ---------------------------------------------------------------------------
// 128x128 GEMM (kept for O-proj: N=1024 gives only 128 blocks at 256^2).
// THREE LDS buffers, stage(t+2) during compute(t), counted vmcnt.
// ---------------------------------------------------------------------------
template <typename OUT>
__global__ __launch_bounds__(256, 2) void gemm_bt(const bf16_t* __restrict__ A,
                                                  const bf16_t* __restrict__ Bw,
                                                  OUT* __restrict__ C,
                                                  int M, int N, int K) {
    __shared__ __attribute__((aligned(16))) bf16_t As[3 * 4096];
    __shared__ __attribute__((aligned(16))) bf16_t Bs[3 * 4096];
    const int tid = threadIdx.x;
    const int l = tid & 63, w = tid >> 6;
    const int lr = l & 15, lg = l >> 4;
    const int wr = w >> 1, wc = w & 1;
    const int nwg = gridDim.x * gridDim.y;
    const int flat = blockIdx.y * gridDim.x + blockIdx.x;
    const int swz = (flat & 7) * (nwg >> 3) + (flat >> 3);
    const int bx = swz % gridDim.x, by = swz / gridDim.x;
    const long m0 = (long)by * 128, n0 = (long)bx * 128;
    const int NT = K >> 5;

    f32x4 acc[4][4] = {};

    auto stage = [&](int buf, int t) {
        const int k0 = t << 5;
#pragma unroll
        for (int p = 0; p < 2; ++p) {
            const int lb = p * 4096 + w * 1024;
            const int lbl = lb + l * 16;
            const int row = lbl >> 6;
            const int col = ((l & 3) ^ ((row >> 2) & 3)) << 3;
            async16(A + (m0 + row) * K + k0 + col, (char*)As + buf * 8192 + lb);
            async16(Bw + (n0 + row) * K + k0 + col, (char*)Bs + buf * 8192 + lb);
        }
    };

    auto compute = [&](int buf) {
        const bf16_t* Ab = As + buf * 4096;
        const bf16_t* Bb = Bs + buf * 4096;
        bf16x8 af[4], bfr[4];
#pragma unroll
        for (int mi = 0; mi < 4; ++mi) {
            const int row = wr * 64 + mi * 16 + lr;
            af[mi] = *(const bf16x8*)(Ab + row * 32 + ((lg ^ ((row >> 2) & 3)) << 3));
        }
#pragma unroll
        for (int ni = 0; ni < 4; ++ni) {
            const int row = wc * 64 + ni * 16 + lr;
            bfr[ni] = *(const bf16x8*)(Bb + row * 32 + ((lg ^ ((row >> 2) & 3)) << 3));
        }
#pragma unroll
        for (int mi = 0; mi < 4; ++mi)
#pragma unroll
            for (int ni = 0; ni < 4; ++ni)
                acc[mi][ni] = MFMA16(af[mi], bfr[ni], acc[mi][ni]);
    };

    stage(0, 0);
    stage(1, 1);
    int bc = 0;
    for (int t = 0; t < NT - 2; ++t) {
        const int bn = (bc + 2 >= 3) ? bc - 1 : bc + 2;
        stage(bn, t + 2);
        asm volatile("s_waitcnt vmcnt(8)" ::: "memory");
        __builtin_amdgcn_s_barrier();
        asm volatile("" ::: "memory");
        compute(bc);
        asm volatile("" ::: "memory");
        __builtin_amdgcn_s_barrier();
        bc = (bc + 1 >= 3) ? 0 : bc + 1;
    }
    asm volatile("s_waitcnt vmcnt(4)" ::: "memory");
    __builtin_amdgcn_s_barrier();
    asm volatile("" ::: "memory");
    compute(bc);
    asm volatile("" ::: "memory");
    __builtin_amdgcn_s_barrier();
    bc = (bc + 1 >= 3) ? 0 : bc + 1;
    asm volatile("s_waitcnt vmcnt(0)" ::: "memory");
    __builtin_amdgcn_s_barrier();
    asm volatile("" ::: "memory");
    compute(bc);

#pragma unroll
    for (int mi = 0; mi < 4; ++mi)
#pragma unroll
        for (int ni = 0; ni < 4; ++ni)
#pragma unroll
            for (int j = 0; j < 4; ++j) {
                long r = m0 + wr * 64 + mi * 16 + lg * 4 + j;
                long c = n0 + wc * 64 + ni * 16 + lr;
                C[r * N + c] = (OUT)acc[mi][ni][j];
            }
}

// ---------------------------------------------------------------------------
// RoPE + reshape. In: Cqkv[8192][3072] (q|k|v channel blocks), cos/sin[2048][32].
// Out: Q[bh][s][64], K[bh][s][64] (rope'd), VT[bh][64][2048] (transposed, with
// within-8-column permutation: position p holds key (p&~7)|rotl3(p&7) so the
// attention kernel's PV B-fragment needs NO cross-lane movement).
// ---------------------------------------------------------------------------
__global__ __launch_bounds__(256) void rope_reshape(const bf16_t* __restrict__ Cq,
                                                    const float* __restrict__ fcos,
                                                    const float* __restrict__ fsin,
                                                    bf16_t* __restrict__ Qo,
                                                    bf16_t* __restrict__ Ko,
                                                    bf16_t* __restrict__ VT) {
    __shared__ __attribute__((aligned(16))) bf16_t vt[64][72];
    const int blk = blockIdx.x;
    const int st = blk & 31, bh = blk >> 5;
    const int h = bh & 15, b = bh >> 4;
    const int s0 = st << 6;
    const int tid = threadIdx.x;
    const int i = tid >> 2, dq = (tid & 3) << 4;
    const int s = s0 + i;

    const bf16_t* base = Cq + (long)(b * 2048 + s) * 3072 + h * 64 + dq;
    bf16x8 q0v = *(const bf16x8*)(base);
    bf16x8 q1v = *(const bf16x8*)(base + 8);
    bf16x8 k0v = *(const bf16x8*)(base + 1024);
    bf16x8 k1v = *(const bf16x8*)(base + 1032);
    bf16x8 v0v = *(const bf16x8*)(base + 2048);
    bf16x8 v1v = *(const bf16x8*)(base + 2056);

    float cs[8], sn[8];
    {
        const float* cp = fcos + (long)s * 32 + (dq >> 1);
        const float* sp = fsin + (long)s * 32 + (dq >> 1);
        float4 a = *(const float4*)cp, b2 = *(const float4*)(cp + 4);
        float4 c = *(const float4*)sp, d2 = *(const float4*)(sp + 4);
        cs[0]=a.x; cs[1]=a.y; cs[2]=a.z; cs[3]=a.w; cs[4]=b2.x; cs[5]=b2.y; cs[6]=b2.z; cs[7]=b2.w;
        sn[0]=c.x; sn[1]=c.y; sn[2]=c.z; sn[3]=c.w; sn[4]=d2.x; sn[5]=d2.y; sn[6]=d2.z; sn[7]=d2.w;
    }

    auto rope8 = [&](bf16x8 v, int fo) -> bf16x8 {
        bf16x8 o;
#pragma unroll
        for (int p = 0; p < 4; ++p) {
            float v0 = (float)v[2 * p], v1 = (float)v[2 * p + 1];
            float c = cs[fo + p], s2 = sn[fo + p];
            o[2 * p]     = (bf16_t)(v0 * c - v1 * s2);
            o[2 * p + 1] = (bf16_t)(v0 * s2 + v1 * c);
        }
        return o;
    };

    bf16x8 qo0 = rope8(q0v, 0), qo1 = rope8(q1v, 4);
    bf16x8 ko0 = rope8(k0v, 0), ko1 = rope8(k1v, 4);

    const long qaddr = ((long)bh * 2048 + s) * 64 + dq;
    *(bf16x8*)(Qo + qaddr) = qo0;
    *(bf16x8*)(Qo + qaddr + 8) = qo1;
    *(bf16x8*)(Ko + qaddr) = ko0;
    *(bf16x8*)(Ko + qaddr + 8) = ko1;

    *(bf16x8*)&vt[i][dq] = v0v;
    *(bf16x8*)&vt[i][dq + 8] = v1v;
    __syncthreads();
    const int d = tid >> 2, sb = (tid & 3) << 4;
    bf16x8 o0, o1;
#pragma unroll
    for (int j = 0; j < 8; ++j) {
        const int f = ((j & 3) << 1) | ((j >> 2) & 1);
        o0[j] = vt[sb + f][d];
        o1[j] = vt[sb + 8 + f][d];
    }
    const long va = ((long)bh * 64 + d) * 2048 + s0 + sb;
    *(bf16x8*)(VT + va) = o0;
    *(bf16x8*)(VT + va + 8) = o1;
}

// ---------------------------------------------------------------------------
// Sliding-window attention v4: whole K/V window staged to LDS up front,
// online softmax per 64-key tile, swapped QK^T, P packs directly into the
// PV B-fragment (V^T stored with within-8 key permutation by rope_reshape).
// ---------------------------------------------------------------------------
__global__ __launch_bounds__(256, 2) void attn_win4(const bf16_t* __restrict__ Q,
                                                    const bf16_t* __restrict__ Kb,
                                                    const bf16_t* __restrict__ VT,
                                                    bf16_t* __restrict__ Ao) {
    __shared__ __attribute__((aligned(16))) bf16_t kld[5 * 4096];
    __shared__ __attribute__((aligned(16))) bf16_t vld[5 * 4096];
    const int raw = blockIdx.x;
    const int mswz = ((raw & 7) << 8) | (raw >> 3);
    const int qt = mswz & 31, bh = mswz >> 5;
    const int h = bh & 15, b = bh >> 4;
    const int l = threadIdx.x & 63, w = threadIdx.x >> 6;
    const int lr = l & 15, lg = l >> 4;
    const int q0 = qt * 64 + w * 16;
    const int q = q0 + lr;
    const int tb = qt - 4;

    const bf16_t* Qp = Q + (long)bh * 2048 * 64;
    const bf16_t* Kp = Kb + (long)bh * 2048 * 64;
    const bf16_t* Vp = VT + (long)bh * 64 * 2048;

#pragma unroll
    for (int u = 0; u < 5; ++u) {
        const int kt = tb + u;
        const int kt64 = (kt < 0 ? 0 : kt) * 64;
#pragma unroll
        for (int part = 0; part < 2; ++part) {
            const int seg = w * 2 + part;
            const int r = seg * 8 + (l >> 3);
            const int sc = (l & 7) ^ ((r >> 1) & 7);
            async16(Kp + (long)(kt64 + r) * 64 + sc * 8,
                    (char*)kld + u * 8192 + seg * 1024);
            async16(Vp + (long)r * 2048 + kt64 + sc * 8,
                    (char*)vld + u * 8192 + seg * 1024);
        }
    }

    const bf16x8 qb0 = *(const bf16x8*)&Qp[q * 64 + lg * 8];
    const bf16x8 qb1 = *(const bf16x8*)&Qp[q * 64 + 32 + lg * 8];

    __syncthreads();

    float mrun = -1000.f, lsum = 0.f;
    f32x4 o0 = {0.f, 0.f, 0.f, 0.f}, o1 = {0.f, 0.f, 0.f, 0.f};
    f32x4 o2 = {0.f, 0.f, 0.f, 0.f}, o3 = {0.f, 0.f, 0.f, 0.f};
    const int swv = (lr >> 1) & 7;

#define QKF(DST, HH, MM)                                                         \
    f32x4 DST; {                                                                 \
        const int row_ = (HH) * 32 + 2 * lr + (MM);                              \
        const int sw_ = (row_ >> 1) & 7;                                         \
        bf16x8 k0_ = *(const bf16x8*)(kbase + row_ * 128 + ((lg ^ sw_) << 4));   \
        bf16x8 k1_ = *(const bf16x8*)(kbase + row_ * 128 + (((4 + lg) ^ sw_) << 4)); \
        f32x4 s_ = {0.f, 0.f, 0.f, 0.f};                                         \
        s_ = MFMA16(k0_, qb0, s_);                                               \
        s_ = MFMA16(k1_, qb1, s_);                                               \
        const int kb_ = k0s + (HH) * 32 + (MM) + lg * 8;                         \
        DST[0] = ((kb_ >= 0) & ((unsigned)(q - kb_) < 256u))         ? s_[0] * 0.125f : -1e30f; \
        DST[1] = ((kb_ + 2 >= 0) & ((unsigned)(q - kb_ - 2) < 256u)) ? s_[1] * 0.125f : -1e30f; \
        DST[2] = ((kb_ + 4 >= 0) & ((unsigned)(q - kb_ - 4) < 256u)) ? s_[2] * 0.125f : -1e30f; \
        DST[3] = ((kb_ + 6 >= 0) & ((unsigned)(q - kb_ - 6) < 256u)) ? s_[3] * 0.125f : -1e30f; \
    }

#define EXV(S_) {                                                                \
        S_[0] = __expf(S_[0] - mnew); S_[1] = __expf(S_[1] - mnew);              \
        S_[2] = __expf(S_[2] - mnew); S_[3] = __expf(S_[3] - mnew);              \
        rs += (S_[0] + S_[1]) + (S_[2] + S_[3]); }

#define PVF(NT, HH, PB) {                                                        \
        bf16x8 va_ = *(const bf16x8*)(vbase + ((NT) * 16 + lr) * 128 +           \
                                      ((((HH) * 4 + lg) ^ swv) << 4));           \
        o##NT = MFMA16(va_, PB, o##NT); }

#pragma unroll
    for (int u = 0; u < 5; ++u) {
        const char* kbase = (const char*)kld + u * 8192;
        const char* vbase = (const char*)vld + u * 8192;
        const int k0s = (tb + u) * 64;

        QKF(sA, 0, 0) QKF(sB, 0, 1) QKF(sC, 1, 0) QKF(sD, 1, 1)

        float tm = fmaxf(fmaxf(fmaxf(sA[0], sA[1]), fmaxf(sA[2], sA[3])),
                         fmaxf(fmaxf(sB[0], sB[1]), fmaxf(sB[2], sB[3])));
        tm = fmaxf(tm, fmaxf(fmaxf(fmaxf(sC[0], sC[1]), fmaxf(sC[2], sC[3])),
                             fmaxf(fmaxf(sD[0], sD[1]), fmaxf(sD[2], sD[3]))));
        tm = fmaxf(tm, __shfl_xor(tm, 16));
        tm = fmaxf(tm, __shfl_xor(tm, 32));
        const float mnew = fmaxf(mrun, tm);
        const float alpha = __expf(mrun - mnew);
        mrun = mnew;

        float rs = 0.f;
        EXV(sA) EXV(sB) EXV(sC) EXV(sD)
        rs += __shfl_xor(rs, 16);
        rs += __shfl_xor(rs, 32);
        lsum = lsum * alpha + rs;

        o0[0] *= alpha; o0[1] *= alpha; o0[2] *= alpha; o0[3] *= alpha;
        o1[0] *= alpha; o1[1] *= alpha; o1[2] *= alpha; o1[3] *= alpha;
        o2[0] *= alpha; o2[1] *= alpha; o2[2] *= alpha; o2[3] *= alpha;
        o3[0] *= alpha; o3[1] *= alpha; o3[2] *= alpha; o3[3] *= alpha;

        bf16x8 pb0, pb1;
        pb0[0] = (bf16_t)sA[0]; pb0[1] = (bf16_t)sA[1]; pb0[2] = (bf16_t)sA[2]; pb0[3] = (bf16_t)sA[3];
        pb0[4] = (bf16_t)sB[0]; pb0[5] = (bf16_t)sB[1]; pb0[6] = (bf16_t)sB[2]; pb0[7] = (bf16_t)sB[3];
        pb1[0] = (bf16_t)sC[0]; pb1[1] = (bf16_t)sC[1]; pb1[2] = (bf16_t)sC[2]; pb1[3] = (bf16_t)sC[3];
        pb1[4] = (bf16_t)sD[0]; pb1[5] = (bf16_t)sD[1]; pb1[6] = (bf16_t)sD[2]; pb1[7] = (bf16_t)sD[3];

        PVF(0, 0, pb0) PVF(1, 0, pb0) PVF(2, 0, pb0) PVF(3, 0, pb0)
        PVF(0, 1, pb1) PVF(1, 1, pb1) PVF(2, 1, pb1) PVF(3, 1, pb1)
    }
#undef QKF
#undef EXV
#undef PVF

    const float rinv = 1.0f / lsum;
    bf16_t* aor = Ao + ((long)(b * 2048) + q) * 1024 + h * 64;
#define EPI(NT, OA_) {                                                           \
        bf16x4 ov_;                                                             \
        ov_[0] = (bf16_t)(OA_[0] * rinv); ov_[1] = (bf16_t)(OA_[1] * rinv);      \
        ov_[2] = (bf16_t)(OA_[2] * rinv); ov_[3] = (bf16_t)(OA_[3] * rinv);      \
        *(bf16x4*)(aor + (NT) * 16 + lg * 4) = ov_; }
    EPI(0, o0) EPI(1, o1) EPI(2, o2) EPI(3, o3)
#undef EPI
}

// ---------------------------------------------------------------------------
extern "C" void kernel_launch(void* const* d_in, const int* in_sizes, int n_in,
                              void* d_out, int out_size, void* d_ws, size_t ws_size,
                              hipStream_t stream) {
    (void)in_sizes; (void)n_in; (void)out_size; (void)ws_size;
    const float* x    = (const float*)d_in[0];
    const float* fcos = (const float*)d_in[1];
    const float* fsin = (const float*)d_in[2];
    const float* wq   = (const float*)d_in[3];
    const float* wk   = (const float*)d_in[4];
    const float* wv   = (const float*)d_in[5];
    const float* wo   = (const float*)d_in[6];
    float* out = (float*)d_out;

    char* ws = (char*)d_ws;
    // layout (bytes): xbf 16MB | wqkv 6MB | wobf 2MB | qkvc 48MB | k 16MB | vt 16MB
    bf16_t* xbf  = (bf16_t*)(ws);
    bf16_t* wqkv = (bf16_t*)(ws + 16777216);
    bf16_t* wobf = (bf16_t*)(ws + 23068672);
    bf16_t* qkvc = (bf16_t*)(ws + 25165824);
    bf16_t* kbuf = (bf16_t*)(ws + 75497472);
    bf16_t* vtb  = (bf16_t*)(ws + 92274688);
    bf16_t* qbuf = xbf;   // xbf dead after GEMM1
    bf16_t* aob  = qkvc;  // qkvc dead after rope

    cvt_kernel<<<4096, 256, 0, stream>>>(x, xbf, 8388608);
    cvt_kernel<<<512, 256, 0, stream>>>(wq, wqkv, 1048576);
    cvt_kernel<<<512, 256, 0, stream>>>(wk, wqkv + 1048576, 1048576);
    cvt_kernel<<<512, 256, 0, stream>>>(wv, wqkv + 2097152, 1048576);
    cvt_kernel<<<512, 256, 0, stream>>>(wo, wobf, 1048576);

    gemm256<bf16_t><<<dim3(12, 32), 512, 0, stream>>>(xbf, wqkv, qkvc, 8192, 3072, 1024);
    rope_reshape<<<2048, 256, 0, stream>>>(qkvc, fcos, fsin, qbuf, kbuf, vtb);
    attn_win4<<<2048, 256, 0, stream>>>(qbuf, kbuf, vtb, aob);
    gemm_bt<float><<<dim3(8, 64), 256, 0, stream>>>(aob, wobf, out, 8192, 1024, 1024);
}

// Round 2
// 154.023 us; speedup vs baseline: 1.0378x; 1.0378x over previous
//
#include <hip/hip_runtime.h>
#include <hip/hip_bf16.h>

// ---------------------------------------------------------------------------
// Sliding-window attention (B=4,S=2048,D=1024,H=16,HD=64,W=256) on gfx950.
// Pipeline: cvt(f32->bf16) -> GEMM(QKV, 256x128 8-phase) -> RoPE+reshape
//           (+permuted V^T) -> flash window attention -> GEMM(O-proj, same).
// ---------------------------------------------------------------------------

typedef __bf16 bf16_t;
typedef __attribute__((ext_vector_type(8))) __bf16 bf16x8;
typedef __attribute__((ext_vector_type(4))) __bf16 bf16x4;
typedef __attribute__((ext_vector_type(4))) float f32x4;

#define MFMA16(a, b, c) __builtin_amdgcn_mfma_f32_16x16x32_bf16((a), (b), (c), 0, 0, 0)

// async global->LDS, 16 bytes per lane. LDS dest is wave-uniform base + lane*16.
__device__ __forceinline__ void async16(const void* g, void* l) {
    __builtin_amdgcn_global_load_lds(
        (const __attribute__((address_space(1))) unsigned int*)g,
        (__attribute__((address_space(3))) unsigned int*)l, 16, 0, 0);
}

#define BAR() do { asm volatile("" ::: "memory"); __builtin_amdgcn_s_barrier(); \
                   asm volatile("" ::: "memory"); } while (0)
#define VMC(N) asm volatile("s_waitcnt vmcnt(" #N ")" ::: "memory")

// ---------------------------------------------------------------------------
// f32 -> bf16 convert, 8 elems/thread
// ---------------------------------------------------------------------------
__global__ __launch_bounds__(256) void cvt_kernel(const float* __restrict__ s,
                                                  bf16_t* __restrict__ d, int n) {
    int i = (blockIdx.x * 256 + threadIdx.x) * 8;
    if (i >= n) return;
    float4 a = *(const float4*)(s + i);
    float4 b = *(const float4*)(s + i + 4);
    bf16x8 o;
    o[0] = (bf16_t)a.x; o[1] = (bf16_t)a.y; o[2] = (bf16_t)a.z; o[3] = (bf16_t)a.w;
    o[4] = (bf16_t)b.x; o[5] = (bf16_t)b.y; o[6] = (bf16_t)b.z; o[7] = (bf16_t)b.w;
    *(bf16x8*)(d + i) = o;
}

// ---------------------------------------------------------------------------
// 256x128 8-phase GEMM: C[M][N] = A[M][K] @ Bw[N][K]^T  (bf16 in, f32 acc).
// 512 threads = 8 waves; wr=w>>1 picks the wave's 64 output rows, wc=w&1 the
// 64 output cols -> per-wave C = 64x64, acc = 64 regs (AGPR).  BK=64.
// LDS 96 KiB: A = 2buf x 2half x (128x64), B = 2buf x (128x64); st_16x32 XOR
// swizzle (byte ^= ((byte>>9)&1)<<5 within 1 KiB subtiles), linear gload_lds
// dest + inverse-swizzled global source + swizzled ds_read (both-sides rule).
//
// Iteration = 2 K-tiles (T=2i buf0, T+1 buf1), 4 phases x 16 MFMA:
//   P1 (tile T, N-half lo): reads A(8 ds)+Blo(4 ds);  stage B1(T+1)   [2 ld]
//   P2 (tile T, N-half hi): reads Bhi(4 ds);          stage A0(T+2)   [4 ld]
//        -> vmcnt(4) certifies tile T+1 (A1 from prev P4 + B1 from P1)
//   P3 (tile T+1, lo):      reads A+Blo;              stage B0(T+2)   [2 ld]
//   P4 (tile T+1, hi):      reads Bhi;                stage A1(T+3)   [4 ld]
//        -> vmcnt(4) certifies tile T+2 (A0 from P2 + B0 from P3)
// Outstanding at each vmcnt: 10 -> drain 6 oldest, keep 4.  Race-freedom:
// each region's overwriting stage issues after the barrier that follows the
// MFMA consuming its last ds_read (last-touch: A@lo-phase, Blo@lo, Bhi@hi).
// ---------------------------------------------------------------------------
template <typename OUT>
__global__ __launch_bounds__(512, 2) void gemm256(const bf16_t* __restrict__ A,
                                                  const bf16_t* __restrict__ Bw,
                                                  OUT* __restrict__ C,
                                                  int M, int N, int K) {
    __shared__ __attribute__((aligned(16))) bf16_t As[32768];   // 2 x 2 x 128x64
    __shared__ __attribute__((aligned(16))) bf16_t Bs[16384];   // 2 x 128x64
    const int tid = threadIdx.x;
    const int l = tid & 63, w = tid >> 6;
    const int lr = l & 15, lg = l >> 4;
    const int wr = w >> 1, wc = w & 1;

    const int nwg = gridDim.x * gridDim.y;
    const int flat = blockIdx.y * gridDim.x + blockIdx.x;
    const int swz = (flat & 7) * (nwg >> 3) + (flat >> 3);
    const int bx = swz % gridDim.x, by = swz / gridDim.x;
    const long m0 = (long)by * 256, n0 = (long)bx * 128;
    const int NT = K >> 6;       // 64-wide K tiles (even, >=4)
    const int NI = NT >> 1;

    // staging decode: unit = 16 KiB = 128 rows x 64 cols. Per thread 2 loads:
    // linear LDS byte p -> unswizzle -> (row r, col c) -> global src address.
    int rS[2], cS[2];
#pragma unroll
    for (int i = 0; i < 2; ++i) {
        const int p  = i * 8192 + w * 1024 + l * 16;
        const int pp = p ^ (((p >> 9) & 1) << 5);
        const int st = pp >> 10;                       // 1 KiB subtile 0..15
        rS[i] = (st >> 1) * 16 + ((pp >> 6) & 15);     // row 0..127
        cS[i] = (st & 1) * 32 + ((pp >> 4) & 3) * 8;   // col 0..63
    }
    const bf16_t* aSrc0 = A  + (m0 + rS[0]) * K + cS[0];
    const bf16_t* aSrc1 = A  + (m0 + rS[1]) * K + cS[1];
    const bf16_t* bSrc0 = Bw + (n0 + rS[0]) * K + cS[0];
    const bf16_t* bSrc1 = Bw + (n0 + rS[1]) * K + cS[1];
    const long hK = 128L * K;

    auto stageA = [&](int b, int h, int t) {
        char* d = (char*)As + b * 32768 + h * 16384 + w * 1024;
        const long o = (long)h * hK + (long)t * 64;
        async16(aSrc0 + o, d);
        async16(aSrc1 + o, d + 8192);
    };
    auto stageB = [&](int b, int t) {
        char* d = (char*)Bs + b * 16384 + w * 1024;
        const long o = (long)t * 64;
        async16(bSrc0 + o, d);
        async16(bSrc1 + o, d + 8192);
    };

    f32x4 acc[4][4] = {};
    bf16x8 af[4][2], blo[2][2], bhi[2][2];
    const int swd = (lr & 8) << 2;    // ds_read swizzle: byte bit5 ^= row bit3

    auto loadA = [&](int b) {
#pragma unroll
        for (int mi = 0; mi < 4; ++mi)
#pragma unroll
            for (int ks = 0; ks < 2; ++ks) {
                const int ra = (wr & 1) * 64 + mi * 16 + lr;
                const int off = ((ra >> 4) * 2 + ks) * 1024 + (ra & 15) * 64 + lg * 16;
                af[mi][ks] = *(const bf16x8*)((const char*)As + b * 32768 +
                                              (wr >> 1) * 16384 + (off ^ swd));
            }
    };
    auto loadB = [&](int b, int nh, bf16x8 (&dst)[2][2]) {
#pragma unroll
        for (int nj = 0; nj < 2; ++nj)
#pragma unroll
            for (int ks = 0; ks < 2; ++ks) {
                const int rb = wc * 64 + (nh * 2 + nj) * 16 + lr;
                const int off = ((rb >> 4) * 2 + ks) * 1024 + (rb & 15) * 64 + lg * 16;
                dst[nj][ks] = *(const bf16x8*)((const char*)Bs + b * 16384 +
                                               (off ^ swd));
            }
    };

#define QMM(NH, BF) do {                                                       \
    __builtin_amdgcn_s_setprio(1);                                             \
    _Pragma("unroll")                                                          \
    for (int mi = 0; mi < 4; ++mi) {                                           \
        acc[mi][(NH)*2]   = MFMA16(af[mi][0], (BF)[0][0], acc[mi][(NH)*2]);    \
        acc[mi][(NH)*2]   = MFMA16(af[mi][1], (BF)[0][1], acc[mi][(NH)*2]);    \
        acc[mi][(NH)*2+1] = MFMA16(af[mi][0], (BF)[1][0], acc[mi][(NH)*2+1]);  \
        acc[mi][(NH)*2+1] = MFMA16(af[mi][1], (BF)[1][1], acc[mi][(NH)*2+1]);  \
    }                                                                          \
    __builtin_amdgcn_s_setprio(0);                                             \
} while (0)

    // ---- prologue: tile0 (6 loads) + tile1's A halves (4); certify tile0 ----
    stageA(0, 0, 0); stageA(0, 1, 0); stageB(0, 0);
    stageA(1, 0, 1); stageA(1, 1, 1);
    VMC(4);          // drain tile0's 6, keep tile1-A's 4
    BAR();

#pragma unroll 1
    for (int it = 0; it < NI - 1; ++it) {
        const int T = it * 2;
        // P1 (tile T, lo)
        loadA(0); loadB(0, 0, blo); stageB(1, T + 1);
        BAR(); QMM(0, blo); BAR();
        // P2 (tile T, hi): certify tile T+1
        loadB(0, 1, bhi); stageA(0, 0, T + 2); stageA(0, 1, T + 2);
        BAR(); QMM(1, bhi); VMC(4); BAR();
        // P3 (tile T+1, lo)
        loadA(1); loadB(1, 0, blo); stageB(0, T + 2);
        BAR(); QMM(0, blo); BAR();
        // P4 (tile T+1, hi): certify tile T+2
        loadB(1, 1, bhi); stageA(1, 0, T + 3); stageA(1, 1, T + 3);
        BAR(); QMM(1, bhi); VMC(4); BAR();
    }

    // ---- final iteration (tiles NT-2, NT-1) ----
    {
        loadA(0); loadB(0, 0, blo); stageB(1, NT - 1);
        BAR(); QMM(0, blo); BAR();
        loadB(0, 1, bhi);
        BAR(); QMM(1, bhi); VMC(0); BAR();   // drain A1(NT-1) + B1(NT-1)
        // last tile: no LDS writers remain -> no barriers needed
        loadA(1); loadB(1, 0, blo);
        QMM(0, blo);
        loadB(1, 1, bhi);
        QMM(1, bhi);
    }
#undef QMM

    // ---- epilogue: fragment row = lg*4+j, col = lr ----
#pragma unroll
    for (int mi = 0; mi < 4; ++mi)
#pragma unroll
        for (int ni = 0; ni < 4; ++ni)
#pragma unroll
            for (int j = 0; j < 4; ++j) {
                long r = m0 + wr * 64 + mi * 16 + lg * 4 + j;
                long c = n0 + wc * 64 + ni * 16 + lr;
                C[r * (long)N + c] = (OUT)acc[mi][ni][j];
            }
}

// ---------------------------------------------------------------------------
// RoPE + reshape. In: Cqkv[8192][3072] (q|k|v channel blocks), cos/sin[2048][32].
// Out: Q[bh][s][64], K[bh][s][64] (rope'd), VT[bh][64][2048] (transposed, with
// within-8-column permutation: position p holds key (p&~7)|rotl3(p&7) so the
// attention kernel's PV B-fragment needs NO cross-lane movement).
// ---------------------------------------------------------------------------
__global__ __launch_bounds__(256) void rope_reshape(const bf16_t* __restrict__ Cq,
                                                    const float* __restrict__ fcos,
                                                    const float* __restrict__ fsin,
                                                    bf16_t* __restrict__ Qo,
                                                    bf16_t* __restrict__ Ko,
                                                    bf16_t* __restrict__ VT) {
    __shared__ __attribute__((aligned(16))) bf16_t vt[64][72];
    const int blk = blockIdx.x;
    const int st = blk & 31, bh = blk >> 5;
    const int h = bh & 15, b = bh >> 4;
    const int s0 = st << 6;
    const int tid = threadIdx.x;
    const int i = tid >> 2, dq = (tid & 3) << 4;
    const int s = s0 + i;

    const bf16_t* base = Cq + (long)(b * 2048 + s) * 3072 + h * 64 + dq;
    bf16x8 q0v = *(const bf16x8*)(base);
    bf16x8 q1v = *(const bf16x8*)(base + 8);
    bf16x8 k0v = *(const bf16x8*)(base + 1024);
    bf16x8 k1v = *(const bf16x8*)(base + 1032);
    bf16x8 v0v = *(const bf16x8*)(base + 2048);
    bf16x8 v1v = *(const bf16x8*)(base + 2056);

    float cs[8], sn[8];
    {
        const float* cp = fcos + (long)s * 32 + (dq >> 1);
        const float* sp = fsin + (long)s * 32 + (dq >> 1);
        float4 a = *(const float4*)cp, b2 = *(const float4*)(cp + 4);
        float4 c = *(const float4*)sp, d2 = *(const float4*)(sp + 4);
        cs[0]=a.x; cs[1]=a.y; cs[2]=a.z; cs[3]=a.w; cs[4]=b2.x; cs[5]=b2.y; cs[6]=b2.z; cs[7]=b2.w;
        sn[0]=c.x; sn[1]=c.y; sn[2]=c.z; sn[3]=c.w; sn[4]=d2.x; sn[5]=d2.y; sn[6]=d2.z; sn[7]=d2.w;
    }

    auto rope8 = [&](bf16x8 v, int fo) -> bf16x8 {
        bf16x8 o;
#pragma unroll
        for (int p = 0; p < 4; ++p) {
            float v0 = (float)v[2 * p], v1 = (float)v[2 * p + 1];
            float c = cs[fo + p], s2 = sn[fo + p];
            o[2 * p]     = (bf16_t)(v0 * c - v1 * s2);
            o[2 * p + 1] = (bf16_t)(v0 * s2 + v1 * c);
        }
        return o;
    };

    bf16x8 qo0 = rope8(q0v, 0), qo1 = rope8(q1v, 4);
    bf16x8 ko0 = rope8(k0v, 0), ko1 = rope8(k1v, 4);

    const long qaddr = ((long)bh * 2048 + s) * 64 + dq;
    *(bf16x8*)(Qo + qaddr) = qo0;
    *(bf16x8*)(Qo + qaddr + 8) = qo1;
    *(bf16x8*)(Ko + qaddr) = ko0;
    *(bf16x8*)(Ko + qaddr + 8) = ko1;

    *(bf16x8*)&vt[i][dq] = v0v;
    *(bf16x8*)&vt[i][dq + 8] = v1v;
    __syncthreads();
    const int d = tid >> 2, sb = (tid & 3) << 4;
    bf16x8 o0, o1;
#pragma unroll
    for (int j = 0; j < 8; ++j) {
        const int f = ((j & 3) << 1) | ((j >> 2) & 1);
        o0[j] = vt[sb + f][d];
        o1[j] = vt[sb + 8 + f][d];
    }
    const long va = ((long)bh * 64 + d) * 2048 + s0 + sb;
    *(bf16x8*)(VT + va) = o0;
    *(bf16x8*)(VT + va + 8) = o1;
}

// ---------------------------------------------------------------------------
// Sliding-window attention v4: whole K/V window staged to LDS up front,
// online softmax per 64-key tile, swapped QK^T, P packs directly into the
// PV B-fragment (V^T stored with within-8 key permutation by rope_reshape).
// ---------------------------------------------------------------------------
__global__ __launch_bounds__(256, 2) void attn_win4(const bf16_t* __restrict__ Q,
                                                    const bf16_t* __restrict__ Kb,
                                                    const bf16_t* __restrict__ VT,
                                                    bf16_t* __restrict__ Ao) {
    __shared__ __attribute__((aligned(16))) bf16_t kld[5 * 4096];
    __shared__ __attribute__((aligned(16))) bf16_t vld[5 * 4096];
    const int raw = blockIdx.x;
    const int mswz = ((raw & 7) << 8) | (raw >> 3);
    const int qt = mswz & 31, bh = mswz >> 5;
    const int h = bh & 15, b = bh >> 4;
    const int l = threadIdx.x & 63, w = threadIdx.x >> 6;
    const int lr = l & 15, lg = l >> 4;
    const int q0 = qt * 64 + w * 16;
    const int q = q0 + lr;
    const int tb = qt - 4;

    const bf16_t* Qp = Q + (long)bh * 2048 * 64;
    const bf16_t* Kp = Kb + (long)bh * 2048 * 64;
    const bf16_t* Vp = VT + (long)bh * 64 * 2048;

#pragma unroll
    for (int u = 0; u < 5; ++u) {
        const int kt = tb + u;
        const int kt64 = (kt < 0 ? 0 : kt) * 64;
#pragma unroll
        for (int part = 0; part < 2; ++part) {
            const int seg = w * 2 + part;
            const int r = seg * 8 + (l >> 3);
            const int sc = (l & 7) ^ ((r >> 1) & 7);
            async16(Kp + (long)(kt64 + r) * 64 + sc * 8,
                    (char*)kld + u * 8192 + seg * 1024);
            async16(Vp + (long)r * 2048 + kt64 + sc * 8,
                    (char*)vld + u * 8192 + seg * 1024);
        }
    }

    const bf16x8 qb0 = *(const bf16x8*)&Qp[q * 64 + lg * 8];
    const bf16x8 qb1 = *(const bf16x8*)&Qp[q * 64 + 32 + lg * 8];

    __syncthreads();

    float mrun = -1000.f, lsum = 0.f;
    f32x4 o0 = {0.f, 0.f, 0.f, 0.f}, o1 = {0.f, 0.f, 0.f, 0.f};
    f32x4 o2 = {0.f, 0.f, 0.f, 0.f}, o3 = {0.f, 0.f, 0.f, 0.f};
    const int swv = (lr >> 1) & 7;

#define QKF(DST, HH, MM)                                                         \
    f32x4 DST; {                                                                 \
        const int row_ = (HH) * 32 + 2 * lr + (MM);                              \
        const int sw_ = (row_ >> 1) & 7;                                         \
        bf16x8 k0_ = *(const bf16x8*)(kbase + row_ * 128 + ((lg ^ sw_) << 4));   \
        bf16x8 k1_ = *(const bf16x8*)(kbase + row_ * 128 + (((4 + lg) ^ sw_) << 4)); \
        f32x4 s_ = {0.f, 0.f, 0.f, 0.f};                                         \
        s_ = MFMA16(k0_, qb0, s_);                                               \
        s_ = MFMA16(k1_, qb1, s_);                                               \
        const int kb_ = k0s + (HH) * 32 + (MM) + lg * 8;                         \
        DST[0] = ((kb_ >= 0) & ((unsigned)(q - kb_) < 256u))         ? s_[0] * 0.125f : -1e30f; \
        DST[1] = ((kb_ + 2 >= 0) & ((unsigned)(q - kb_ - 2) < 256u)) ? s_[1] * 0.125f : -1e30f; \
        DST[2] = ((kb_ + 4 >= 0) & ((unsigned)(q - kb_ - 4) < 256u)) ? s_[2] * 0.125f : -1e30f; \
        DST[3] = ((kb_ + 6 >= 0) & ((unsigned)(q - kb_ - 6) < 256u)) ? s_[3] * 0.125f : -1e30f; \
    }

#define EXV(S_) {                                                                \
        S_[0] = __expf(S_[0] - mnew); S_[1] = __expf(S_[1] - mnew);              \
        S_[2] = __expf(S_[2] - mnew); S_[3] = __expf(S_[3] - mnew);              \
        rs += (S_[0] + S_[1]) + (S_[2] + S_[3]); }

#define PVF(NT, HH, PB) {                                                        \
        bf16x8 va_ = *(const bf16x8*)(vbase + ((NT) * 16 + lr) * 128 +           \
                                      ((((HH) * 4 + lg) ^ swv) << 4));           \
        o##NT = MFMA16(va_, PB, o##NT); }

#pragma unroll
    for (int u = 0; u < 5; ++u) {
        const char* kbase = (const char*)kld + u * 8192;
        const char* vbase = (const char*)vld + u * 8192;
        const int k0s = (tb + u) * 64;

        QKF(sA, 0, 0) QKF(sB, 0, 1) QKF(sC, 1, 0) QKF(sD, 1, 1)

        float tm = fmaxf(fmaxf(fmaxf(sA[0], sA[1]), fmaxf(sA[2], sA[3])),
                         fmaxf(fmaxf(sB[0], sB[1]), fmaxf(sB[2], sB[3])));
        tm = fmaxf(tm, fmaxf(fmaxf(fmaxf(sC[0], sC[1]), fmaxf(sC[2], sC[3])),
                             fmaxf(fmaxf(sD[0], sD[1]), fmaxf(sD[2], sD[3]))));
        tm = fmaxf(tm, __shfl_xor(tm, 16));
        tm = fmaxf(tm, __shfl_xor(tm, 32));
        const float mnew = fmaxf(mrun, tm);
        const float alpha = __expf(mrun - mnew);
        mrun = mnew;

        float rs = 0.f;
        EXV(sA) EXV(sB) EXV(sC) EXV(sD)
        rs += __shfl_xor(rs, 16);
        rs += __shfl_xor(rs, 32);
        lsum = lsum * alpha + rs;

        o0[0] *= alpha; o0[1] *= alpha; o0[2] *= alpha; o0[3] *= alpha;
        o1[0] *= alpha; o1[1] *= alpha; o1[2] *= alpha; o1[3] *= alpha;
        o2[0] *= alpha; o2[1] *= alpha; o2[2] *= alpha; o2[3] *= alpha;
        o3[0] *= alpha; o3[1] *= alpha; o3[2] *= alpha; o3[3] *= alpha;

        bf16x8 pb0, pb1;
        pb0[0] = (bf16_t)sA[0]; pb0[1] = (bf16_t)sA[1]; pb0[2] = (bf16_t)sA[2]; pb0[3] = (bf16_t)sA[3];
        pb0[4] = (bf16_t)sB[0]; pb0[5] = (bf16_t)sB[1]; pb0[6] = (bf16_t)sB[2]; pb0[7] = (bf16_t)sB[3];
        pb1[0] = (bf16_t)sC[0]; pb1[1] = (bf16_t)sC[1]; pb1[2] = (bf16_t)sC[2]; pb1[3] = (bf16_t)sC[3];
        pb1[4] = (bf16_t)sD[0]; pb1[5] = (bf16_t)sD[1]; pb1[6] = (bf16_t)sD[2]; pb1[7] = (bf16_t)sD[3];

        PVF(0, 0, pb0) PVF(1, 0, pb0) PVF(2, 0, pb0) PVF(3, 0, pb0)
        PVF(0, 1, pb1) PVF(1, 1, pb1) PVF(2, 1, pb1) PVF(3, 1, pb1)
    }
#undef QKF
#undef EXV
#undef PVF

    const float rinv = 1.0f / lsum;
    bf16_t* aor = Ao + ((long)(b * 2048) + q) * 1024 + h * 64;
#define EPI(NT, OA_) {                                                           \
        bf16x4 ov_;                                                             \
        ov_[0] = (bf16_t)(OA_[0] * rinv); ov_[1] = (bf16_t)(OA_[1] * rinv);      \
        ov_[2] = (bf16_t)(OA_[2] * rinv); ov_[3] = (bf16_t)(OA_[3] * rinv);      \
        *(bf16x4*)(aor + (NT) * 16 + lg * 4) = ov_; }
    EPI(0, o0) EPI(1, o1) EPI(2, o2) EPI(3, o3)
#undef EPI
}

// ---------------------------------------------------------------------------
extern "C" void kernel_launch(void* const* d_in, const int* in_sizes, int n_in,
                              void* d_out, int out_size, void* d_ws, size_t ws_size,
                              hipStream_t stream) {
    (void)in_sizes; (void)n_in; (void)out_size; (void)ws_size;
    const float* x    = (const float*)d_in[0];
    const float* fcos = (const float*)d_in[1];
    const float* fsin = (const float*)d_in[2];
    const float* wq   = (const float*)d_in[3];
    const float* wk   = (const float*)d_in[4];
    const float* wv   = (const float*)d_in[5];
    const float* wo   = (const float*)d_in[6];
    float* out = (float*)d_out;

    char* ws = (char*)d_ws;
    // layout (bytes): xbf 16MB | wqkv 6MB | wobf 2MB | qkvc 48MB | k 16MB | vt 16MB
    bf16_t* xbf  = (bf16_t*)(ws);
    bf16_t* wqkv = (bf16_t*)(ws + 16777216);
    bf16_t* wobf = (bf16_t*)(ws + 23068672);
    bf16_t* qkvc = (bf16_t*)(ws + 25165824);
    bf16_t* kbuf = (bf16_t*)(ws + 75497472);
    bf16_t* vtb  = (bf16_t*)(ws + 92274688);
    bf16_t* qbuf = xbf;   // xbf dead after GEMM1
    bf16_t* aob  = qkvc;  // qkvc dead after rope

    cvt_kernel<<<4096, 256, 0, stream>>>(x, xbf, 8388608);
    cvt_kernel<<<512, 256, 0, stream>>>(wq, wqkv, 1048576);
    cvt_kernel<<<512, 256, 0, stream>>>(wk, wqkv + 1048576, 1048576);
    cvt_kernel<<<512, 256, 0, stream>>>(wv, wqkv + 2097152, 1048576);
    cvt_kernel<<<512, 256, 0, stream>>>(wo, wobf, 1048576);

    // QKV: grid (N/128, M/256) = (24, 32) = 768 blocks = 3 exact rounds
    gemm256<bf16_t><<<dim3(24, 32), 512, 0, stream>>>(xbf, wqkv, qkvc, 8192, 3072, 1024);
    rope_reshape<<<2048, 256, 0, stream>>>(qkvc, fcos, fsin, qbuf, kbuf, vtb);
    attn_win4<<<2048, 256, 0, stream>>>(qbuf, kbuf, vtb, aob);
    // O-proj: grid (8, 32) = 256 blocks = 1 exact round
    gemm256<float><<<dim3(8, 32), 512, 0, stream>>>(aob, wobf, out, 8192, 1024, 1024);
}

// Round 3
// 147.114 us; speedup vs baseline: 1.0866x; 1.0470x over previous
//
#include <hip/hip_runtime.h>
#include <hip/hip_bf16.h>

// ---------------------------------------------------------------------------
// Sliding-window attention (B=4,S=2048,D=1024,H=16,HD=64,W=256) on gfx950.
// Pipeline: cvt(f32->bf16) -> GEMM(QKV, 256x128 triple-buffered deep-prefetch)
//           -> RoPE+reshape (+permuted V^T) -> flash window attention
//           -> GEMM(O-proj, same kernel).
// ---------------------------------------------------------------------------

typedef __bf16 bf16_t;
typedef __attribute__((ext_vector_type(8))) __bf16 bf16x8;
typedef __attribute__((ext_vector_type(4))) __bf16 bf16x4;
typedef __attribute__((ext_vector_type(4))) float f32x4;

#define MFMA16(a, b, c) __builtin_amdgcn_mfma_f32_16x16x32_bf16((a), (b), (c), 0, 0, 0)

// async global->LDS, 16 bytes per lane. LDS dest is wave-uniform base + lane*16.
__device__ __forceinline__ void async16(const void* g, void* l) {
    __builtin_amdgcn_global_load_lds(
        (const __attribute__((address_space(1))) unsigned int*)g,
        (__attribute__((address_space(3))) unsigned int*)l, 16, 0, 0);
}

#define BAR() do { asm volatile("" ::: "memory"); __builtin_amdgcn_s_barrier(); \
                   asm volatile("" ::: "memory"); } while (0)
#define VMC(N) asm volatile("s_waitcnt vmcnt(" #N ")" ::: "memory")

// ---------------------------------------------------------------------------
// f32 -> bf16 convert, 8 elems/thread
// ---------------------------------------------------------------------------
__global__ __launch_bounds__(256) void cvt_kernel(const float* __restrict__ s,
                                                  bf16_t* __restrict__ d, int n) {
    int i = (blockIdx.x * 256 + threadIdx.x) * 8;
    if (i >= n) return;
    float4 a = *(const float4*)(s + i);
    float4 b = *(const float4*)(s + i + 4);
    bf16x8 o;
    o[0] = (bf16_t)a.x; o[1] = (bf16_t)a.y; o[2] = (bf16_t)a.z; o[3] = (bf16_t)a.w;
    o[4] = (bf16_t)b.x; o[5] = (bf16_t)b.y; o[6] = (bf16_t)b.z; o[7] = (bf16_t)b.w;
    *(bf16x8*)(d + i) = o;
}

// ---------------------------------------------------------------------------
// 256x128 GEMM: C[M][N] = A[M][K] @ Bw[N][K]^T  (bf16 in, f32 acc).
// 512 threads = 8 waves; per-wave C = 64x64 (acc = 64 regs). BK=64.
// TRIPLE-buffered LDS (144 KiB): A = 3buf x 2half x (128x64), B = 3buf x
// (128x64); st_16x32 XOR swizzle (byte ^= ((byte>>9)&1)<<5 within 1 KiB
// subtiles), linear gload_lds dest + inverse-swizzled global source +
// swizzled ds_read (both-sides rule).
//
// Deep prefetch (the R2 fix): while computing tile t, tile t+1 is fully
// resident and tile t+2 is in flight (6 loads). Two phases per tile:
//   lo: loadA(8 ds)+loadBlo(4 ds); stage A0,A1(t+2) [4 ld]; BAR; 16 MFMA; BAR
//   hi: loadBhi(4 ds);             stage B(t+2)     [2 ld]; BAR; 16 MFMA;
//       VMC(6); BAR     <- drains tile t+1's 6 loads (issued 2-3 phases ago,
//                          ~800-1200cy of latency cover), keeps t+2's 6.
// Race-freedom: buf(t+2) = buf(t-1); tile t-1's last ds_read is forced
// complete (MFMA data-dep) before iteration t-1's trailing barrier, which
// precedes iteration t's stage issue in every wave.
// Epilogue: at t=NT-3 drain to 0; last two tiles read with no barriers.
// ---------------------------------------------------------------------------
template <typename OUT>
__global__ __launch_bounds__(512, 2) void gemm256(const bf16_t* __restrict__ A,
                                                  const bf16_t* __restrict__ Bw,
                                                  OUT* __restrict__ C,
                                                  int M, int N, int K) {
    __shared__ __attribute__((aligned(16))) bf16_t As[49152];   // 3 x 2 x 128x64
    __shared__ __attribute__((aligned(16))) bf16_t Bs[24576];   // 3 x 128x64
    const int tid = threadIdx.x;
    const int l = tid & 63, w = tid >> 6;
    const int lr = l & 15, lg = l >> 4;
    const int wr = w >> 1, wc = w & 1;

    const int nwg = gridDim.x * gridDim.y;
    const int flat = blockIdx.y * gridDim.x + blockIdx.x;
    const int swz = (flat & 7) * (nwg >> 3) + (flat >> 3);
    const int bx = swz % gridDim.x, by = swz / gridDim.x;
    const long m0 = (long)by * 256, n0 = (long)bx * 128;
    const int NT = K >> 6;       // 64-wide K tiles (>= 4)

    // staging decode: unit = 16 KiB = 128 rows x 64 cols. Per thread 2 loads:
    // linear LDS byte p -> unswizzle -> (row r, col c) -> global src address.
    int rS[2], cS[2];
#pragma unroll
    for (int i = 0; i < 2; ++i) {
        const int p  = i * 8192 + w * 1024 + l * 16;
        const int pp = p ^ (((p >> 9) & 1) << 5);
        const int st = pp >> 10;                       // 1 KiB subtile 0..15
        rS[i] = (st >> 1) * 16 + ((pp >> 6) & 15);     // row 0..127
        cS[i] = (st & 1) * 32 + ((pp >> 4) & 3) * 8;   // col 0..63
    }
    const bf16_t* aSrc0 = A  + (m0 + rS[0]) * K + cS[0];
    const bf16_t* aSrc1 = A  + (m0 + rS[1]) * K + cS[1];
    const bf16_t* bSrc0 = Bw + (n0 + rS[0]) * K + cS[0];
    const bf16_t* bSrc1 = Bw + (n0 + rS[1]) * K + cS[1];
    const long hK = 128L * K;

    auto stageA = [&](int b, int h, int t) {
        char* d = (char*)As + b * 32768 + h * 16384 + w * 1024;
        const long o = (long)h * hK + (long)t * 64;
        async16(aSrc0 + o, d);
        async16(aSrc1 + o, d + 8192);
    };
    auto stageB = [&](int b, int t) {
        char* d = (char*)Bs + b * 16384 + w * 1024;
        const long o = (long)t * 64;
        async16(bSrc0 + o, d);
        async16(bSrc1 + o, d + 8192);
    };

    f32x4 acc[4][4] = {};
    bf16x8 af[4][2], blo[2][2], bhi[2][2];
    const int swd = (lr & 8) << 2;    // ds_read swizzle: byte bit5 ^= row bit3

    auto loadA = [&](int b) {
#pragma unroll
        for (int mi = 0; mi < 4; ++mi)
#pragma unroll
            for (int ks = 0; ks < 2; ++ks) {
                const int ra = (wr & 1) * 64 + mi * 16 + lr;
                const int off = ((ra >> 4) * 2 + ks) * 1024 + (ra & 15) * 64 + lg * 16;
                af[mi][ks] = *(const bf16x8*)((const char*)As + b * 32768 +
                                              (wr >> 1) * 16384 + (off ^ swd));
            }
    };
    auto loadB = [&](int b, int nh, bf16x8 (&dst)[2][2]) {
#pragma unroll
        for (int nj = 0; nj < 2; ++nj)
#pragma unroll
            for (int ks = 0; ks < 2; ++ks) {
                const int rb = wc * 64 + (nh * 2 + nj) * 16 + lr;
                const int off = ((rb >> 4) * 2 + ks) * 1024 + (rb & 15) * 64 + lg * 16;
                dst[nj][ks] = *(const bf16x8*)((const char*)Bs + b * 16384 +
                                               (off ^ swd));
            }
    };

#define QMM(NH, BF) do {                                                       \
    __builtin_amdgcn_s_setprio(1);                                             \
    _Pragma("unroll")                                                          \
    for (int mi = 0; mi < 4; ++mi) {                                           \
        acc[mi][(NH)*2]   = MFMA16(af[mi][0], (BF)[0][0], acc[mi][(NH)*2]);    \
        acc[mi][(NH)*2]   = MFMA16(af[mi][1], (BF)[0][1], acc[mi][(NH)*2]);    \
        acc[mi][(NH)*2+1] = MFMA16(af[mi][0], (BF)[1][0], acc[mi][(NH)*2+1]);  \
        acc[mi][(NH)*2+1] = MFMA16(af[mi][1], (BF)[1][1], acc[mi][(NH)*2+1]);  \
    }                                                                          \
    __builtin_amdgcn_s_setprio(0);                                             \
} while (0)

    // ---- prologue: tiles 0 and 1 fully staged (6 loads each, tile-major
    //      order so FIFO drain certifies tile 0 first) ----
    stageA(0, 0, 0); stageA(0, 1, 0); stageB(0, 0);
    stageA(1, 0, 1); stageA(1, 1, 1); stageB(1, 1);
    VMC(6);          // tile0 resident; tile1's 6 in flight
    BAR();

    int bc = 0;                       // buffer of tile t
#pragma unroll 1
    for (int t = 0; t < NT - 2; ++t) {
        const int bn = (bc + 2 >= 3) ? bc - 1 : bc + 2;   // buf of tile t+2
        // lo phase
        loadA(bc); loadB(bc, 0, blo); stageA(bn, 0, t + 2); stageA(bn, 1, t + 2);
        BAR(); QMM(0, blo); BAR();
        // hi phase: certify tile t+1 (drain its 6, keep t+2's 6)
        loadB(bc, 1, bhi); stageB(bn, t + 2);
        BAR(); QMM(1, bhi);
        if (t < NT - 3) { VMC(6); } else { VMC(0); }
        BAR();
        bc = (bc + 1 >= 3) ? 0 : bc + 1;
    }

    // ---- tiles NT-2, NT-1: fully resident, no LDS writers -> no barriers ----
    {
        loadA(bc); loadB(bc, 0, blo);
        QMM(0, blo);
        loadB(bc, 1, bhi);
        QMM(1, bhi);
        const int b2 = (bc + 1 >= 3) ? 0 : bc + 1;
        loadA(b2); loadB(b2, 0, blo);
        QMM(0, blo);
        loadB(b2, 1, bhi);
        QMM(1, bhi);
    }
#undef QMM

    // ---- epilogue: fragment row = lg*4+j, col = lr ----
#pragma unroll
    for (int mi = 0; mi < 4; ++mi)
#pragma unroll
        for (int ni = 0; ni < 4; ++ni)
#pragma unroll
            for (int j = 0; j < 4; ++j) {
                long r = m0 + wr * 64 + mi * 16 + lg * 4 + j;
                long c = n0 + wc * 64 + ni * 16 + lr;
                C[r * (long)N + c] = (OUT)acc[mi][ni][j];
            }
}

// ---------------------------------------------------------------------------
// RoPE + reshape. In: Cqkv[8192][3072] (q|k|v channel blocks), cos/sin[2048][32].
// Out: Q[bh][s][64], K[bh][s][64] (rope'd), VT[bh][64][2048] (transposed, with
// within-8-column permutation: position p holds key (p&~7)|rotl3(p&7) so the
// attention kernel's PV B-fragment needs NO cross-lane movement).
// ---------------------------------------------------------------------------
__global__ __launch_bounds__(256) void rope_reshape(const bf16_t* __restrict__ Cq,
                                                    const float* __restrict__ fcos,
                                                    const float* __restrict__ fsin,
                                                    bf16_t* __restrict__ Qo,
                                                    bf16_t* __restrict__ Ko,
                                                    bf16_t* __restrict__ VT) {
    __shared__ __attribute__((aligned(16))) bf16_t vt[64][72];
    const int blk = blockIdx.x;
    const int st = blk & 31, bh = blk >> 5;
    const int h = bh & 15, b = bh >> 4;
    const int s0 = st << 6;
    const int tid = threadIdx.x;
    const int i = tid >> 2, dq = (tid & 3) << 4;
    const int s = s0 + i;

    const bf16_t* base = Cq + (long)(b * 2048 + s) * 3072 + h * 64 + dq;
    bf16x8 q0v = *(const bf16x8*)(base);
    bf16x8 q1v = *(const bf16x8*)(base + 8);
    bf16x8 k0v = *(const bf16x8*)(base + 1024);
    bf16x8 k1v = *(const bf16x8*)(base + 1032);
    bf16x8 v0v = *(const bf16x8*)(base + 2048);
    bf16x8 v1v = *(const bf16x8*)(base + 2056);

    float cs[8], sn[8];
    {
        const float* cp = fcos + (long)s * 32 + (dq >> 1);
        const float* sp = fsin + (long)s * 32 + (dq >> 1);
        float4 a = *(const float4*)cp, b2 = *(const float4*)(cp + 4);
        float4 c = *(const float4*)sp, d2 = *(const float4*)(sp + 4);
        cs[0]=a.x; cs[1]=a.y; cs[2]=a.z; cs[3]=a.w; cs[4]=b2.x; cs[5]=b2.y; cs[6]=b2.z; cs[7]=b2.w;
        sn[0]=c.x; sn[1]=c.y; sn[2]=c.z; sn[3]=c.w; sn[4]=d2.x; sn[5]=d2.y; sn[6]=d2.z; sn[7]=d2.w;
    }

    auto rope8 = [&](bf16x8 v, int fo) -> bf16x8 {
        bf16x8 o;
#pragma unroll
        for (int p = 0; p < 4; ++p) {
            float v0 = (float)v[2 * p], v1 = (float)v[2 * p + 1];
            float c = cs[fo + p], s2 = sn[fo + p];
            o[2 * p]     = (bf16_t)(v0 * c - v1 * s2);
            o[2 * p + 1] = (bf16_t)(v0 * s2 + v1 * c);
        }
        return o;
    };

    bf16x8 qo0 = rope8(q0v, 0), qo1 = rope8(q1v, 4);
    bf16x8 ko0 = rope8(k0v, 0), ko1 = rope8(k1v, 4);

    const long qaddr = ((long)bh * 2048 + s) * 64 + dq;
    *(bf16x8*)(Qo + qaddr) = qo0;
    *(bf16x8*)(Qo + qaddr + 8) = qo1;
    *(bf16x8*)(Ko + qaddr) = ko0;
    *(bf16x8*)(Ko + qaddr + 8) = ko1;

    *(bf16x8*)&vt[i][dq] = v0v;
    *(bf16x8*)&vt[i][dq + 8] = v1v;
    __syncthreads();
    const int d = tid >> 2, sb = (tid & 3) << 4;
    bf16x8 o0, o1;
#pragma unroll
    for (int j = 0; j < 8; ++j) {
        const int f = ((j & 3) << 1) | ((j >> 2) & 1);
        o0[j] = vt[sb + f][d];
        o1[j] = vt[sb + 8 + f][d];
    }
    const long va = ((long)bh * 64 + d) * 2048 + s0 + sb;
    *(bf16x8*)(VT + va) = o0;
    *(bf16x8*)(VT + va + 8) = o1;
}

// ---------------------------------------------------------------------------
// Sliding-window attention v4: whole K/V window staged to LDS up front,
// online softmax per 64-key tile, swapped QK^T, P packs directly into the
// PV B-fragment (V^T stored with within-8 key permutation by rope_reshape).
// ---------------------------------------------------------------------------
__global__ __launch_bounds__(256, 2) void attn_win4(const bf16_t* __restrict__ Q,
                                                    const bf16_t* __restrict__ Kb,
                                                    const bf16_t* __restrict__ VT,
                                                    bf16_t* __restrict__ Ao) {
    __shared__ __attribute__((aligned(16))) bf16_t kld[5 * 4096];
    __shared__ __attribute__((aligned(16))) bf16_t vld[5 * 4096];
    const int raw = blockIdx.x;
    const int mswz = ((raw & 7) << 8) | (raw >> 3);
    const int qt = mswz & 31, bh = mswz >> 5;
    const int h = bh & 15, b = bh >> 4;
    const int l = threadIdx.x & 63, w = threadIdx.x >> 6;
    const int lr = l & 15, lg = l >> 4;
    const int q0 = qt * 64 + w * 16;
    const int q = q0 + lr;
    const int tb = qt - 4;

    const bf16_t* Qp = Q + (long)bh * 2048 * 64;
    const bf16_t* Kp = Kb + (long)bh * 2048 * 64;
    const bf16_t* Vp = VT + (long)bh * 64 * 2048;

#pragma unroll
    for (int u = 0; u < 5; ++u) {
        const int kt = tb + u;
        const int kt64 = (kt < 0 ? 0 : kt) * 64;
#pragma unroll
        for (int part = 0; part < 2; ++part) {
            const int seg = w * 2 + part;
            const int r = seg * 8 + (l >> 3);
            const int sc = (l & 7) ^ ((r >> 1) & 7);
            async16(Kp + (long)(kt64 + r) * 64 + sc * 8,
                    (char*)kld + u * 8192 + seg * 1024);
            async16(Vp + (long)r * 2048 + kt64 + sc * 8,
                    (char*)vld + u * 8192 + seg * 1024);
        }
    }

    const bf16x8 qb0 = *(const bf16x8*)&Qp[q * 64 + lg * 8];
    const bf16x8 qb1 = *(const bf16x8*)&Qp[q * 64 + 32 + lg * 8];

    __syncthreads();

    float mrun = -1000.f, lsum = 0.f;
    f32x4 o0 = {0.f, 0.f, 0.f, 0.f}, o1 = {0.f, 0.f, 0.f, 0.f};
    f32x4 o2 = {0.f, 0.f, 0.f, 0.f}, o3 = {0.f, 0.f, 0.f, 0.f};
    const int swv = (lr >> 1) & 7;

#define QKF(DST, HH, MM)                                                         \
    f32x4 DST; {                                                                 \
        const int row_ = (HH) * 32 + 2 * lr + (MM);                              \
        const int sw_ = (row_ >> 1) & 7;                                         \
        bf16x8 k0_ = *(const bf16x8*)(kbase + row_ * 128 + ((lg ^ sw_) << 4));   \
        bf16x8 k1_ = *(const bf16x8*)(kbase + row_ * 128 + (((4 + lg) ^ sw_) << 4)); \
        f32x4 s_ = {0.f, 0.f, 0.f, 0.f};                                         \
        s_ = MFMA16(k0_, qb0, s_);                                               \
        s_ = MFMA16(k1_, qb1, s_);                                               \
        const int kb_ = k0s + (HH) * 32 + (MM) + lg * 8;                         \
        DST[0] = ((kb_ >= 0) & ((unsigned)(q - kb_) < 256u))         ? s_[0] * 0.125f : -1e30f; \
        DST[1] = ((kb_ + 2 >= 0) & ((unsigned)(q - kb_ - 2) < 256u)) ? s_[1] * 0.125f : -1e30f; \
        DST[2] = ((kb_ + 4 >= 0) & ((unsigned)(q - kb_ - 4) < 256u)) ? s_[2] * 0.125f : -1e30f; \
        DST[3] = ((kb_ + 6 >= 0) & ((unsigned)(q - kb_ - 6) < 256u)) ? s_[3] * 0.125f : -1e30f; \
    }

#define EXV(S_) {                                                                \
        S_[0] = __expf(S_[0] - mnew); S_[1] = __expf(S_[1] - mnew);              \
        S_[2] = __expf(S_[2] - mnew); S_[3] = __expf(S_[3] - mnew);              \
        rs += (S_[0] + S_[1]) + (S_[2] + S_[3]); }

#define PVF(NT, HH, PB) {                                                        \
        bf16x8 va_ = *(const bf16x8*)(vbase + ((NT) * 16 + lr) * 128 +           \
                                      ((((HH) * 4 + lg) ^ swv) << 4));           \
        o##NT = MFMA16(va_, PB, o##NT); }

#pragma unroll
    for (int u = 0; u < 5; ++u) {
        const char* kbase = (const char*)kld + u * 8192;
        const char* vbase = (const char*)vld + u * 8192;
        const int k0s = (tb + u) * 64;

        QKF(sA, 0, 0) QKF(sB, 0, 1) QKF(sC, 1, 0) QKF(sD, 1, 1)

        float tm = fmaxf(fmaxf(fmaxf(sA[0], sA[1]), fmaxf(sA[2], sA[3])),
                         fmaxf(fmaxf(sB[0], sB[1]), fmaxf(sB[2], sB[3])));
        tm = fmaxf(tm, fmaxf(fmaxf(fmaxf(sC[0], sC[1]), fmaxf(sC[2], sC[3])),
                             fmaxf(fmaxf(sD[0], sD[1]), fmaxf(sD[2], sD[3]))));
        tm = fmaxf(tm, __shfl_xor(tm, 16));
        tm = fmaxf(tm, __shfl_xor(tm, 32));
        const float mnew = fmaxf(mrun, tm);
        const float alpha = __expf(mrun - mnew);
        mrun = mnew;

        float rs = 0.f;
        EXV(sA) EXV(sB) EXV(sC) EXV(sD)
        rs += __shfl_xor(rs, 16);
        rs += __shfl_xor(rs, 32);
        lsum = lsum * alpha + rs;

        o0[0] *= alpha; o0[1] *= alpha; o0[2] *= alpha; o0[3] *= alpha;
        o1[0] *= alpha; o1[1] *= alpha; o1[2] *= alpha; o1[3] *= alpha;
        o2[0] *= alpha; o2[1] *= alpha; o2[2] *= alpha; o2[3] *= alpha;
        o3[0] *= alpha; o3[1] *= alpha; o3[2] *= alpha; o3[3] *= alpha;

        bf16x8 pb0, pb1;
        pb0[0] = (bf16_t)sA[0]; pb0[1] = (bf16_t)sA[1]; pb0[2] = (bf16_t)sA[2]; pb0[3] = (bf16_t)sA[3];
        pb0[4] = (bf16_t)sB[0]; pb0[5] = (bf16_t)sB[1]; pb0[6] = (bf16_t)sB[2]; pb0[7] = (bf16_t)sB[3];
        pb1[0] = (bf16_t)sC[0]; pb1[1] = (bf16_t)sC[1]; pb1[2] = (bf16_t)sC[2]; pb1[3] = (bf16_t)sC[3];
        pb1[4] = (bf16_t)sD[0]; pb1[5] = (bf16_t)sD[1]; pb1[6] = (bf16_t)sD[2]; pb1[7] = (bf16_t)sD[3];

        PVF(0, 0, pb0) PVF(1, 0, pb0) PVF(2, 0, pb0) PVF(3, 0, pb0)
        PVF(0, 1, pb1) PVF(1, 1, pb1) PVF(2, 1, pb1) PVF(3, 1, pb1)
    }
#undef QKF
#undef EXV
#undef PVF

    const float rinv = 1.0f / lsum;
    bf16_t* aor = Ao + ((long)(b * 2048) + q) * 1024 + h * 64;
#define EPI(NT, OA_) {                                                           \
        bf16x4 ov_;                                                             \
        ov_[0] = (bf16_t)(OA_[0] * rinv); ov_[1] = (bf16_t)(OA_[1] * rinv);      \
        ov_[2] = (bf16_t)(OA_[2] * rinv); ov_[3] = (bf16_t)(OA_[3] * rinv);      \
        *(bf16x4*)(aor + (NT) * 16 + lg * 4) = ov_; }
    EPI(0, o0) EPI(1, o1) EPI(2, o2) EPI(3, o3)
#undef EPI
}

// ---------------------------------------------------------------------------
extern "C" void kernel_launch(void* const* d_in, const int* in_sizes, int n_in,
                              void* d_out, int out_size, void* d_ws, size_t ws_size,
                              hipStream_t stream) {
    (void)in_sizes; (void)n_in; (void)out_size; (void)ws_size;
    const float* x    = (const float*)d_in[0];
    const float* fcos = (const float*)d_in[1];
    const float* fsin = (const float*)d_in[2];
    const float* wq   = (const float*)d_in[3];
    const float* wk   = (const float*)d_in[4];
    const float* wv   = (const float*)d_in[5];
    const float* wo   = (const float*)d_in[6];
    float* out = (float*)d_out;

    char* ws = (char*)d_ws;
    // layout (bytes): xbf 16MB | wqkv 6MB | wobf 2MB | qkvc 48MB | k 16MB | vt 16MB
    bf16_t* xbf  = (bf16_t*)(ws);
    bf16_t* wqkv = (bf16_t*)(ws + 16777216);
    bf16_t* wobf = (bf16_t*)(ws + 23068672);
    bf16_t* qkvc = (bf16_t*)(ws + 25165824);
    bf16_t* kbuf = (bf16_t*)(ws + 75497472);
    bf16_t* vtb  = (bf16_t*)(ws + 92274688);
    bf16_t* qbuf = xbf;   // xbf dead after GEMM1
    bf16_t* aob  = qkvc;  // qkvc dead after rope

    cvt_kernel<<<4096, 256, 0, stream>>>(x, xbf, 8388608);
    cvt_kernel<<<512, 256, 0, stream>>>(wq, wqkv, 1048576);
    cvt_kernel<<<512, 256, 0, stream>>>(wk, wqkv + 1048576, 1048576);
    cvt_kernel<<<512, 256, 0, stream>>>(wv, wqkv + 2097152, 1048576);
    cvt_kernel<<<512, 256, 0, stream>>>(wo, wobf, 1048576);

    // QKV: grid (N/128, M/256) = (24, 32) = 768 blocks = 3 exact rounds
    gemm256<bf16_t><<<dim3(24, 32), 512, 0, stream>>>(xbf, wqkv, qkvc, 8192, 3072, 1024);
    rope_reshape<<<2048, 256, 0, stream>>>(qkvc, fcos, fsin, qbuf, kbuf, vtb);
    attn_win4<<<2048, 256, 0, stream>>>(qbuf, kbuf, vtb, aob);
    // O-proj: grid (8, 32) = 256 blocks = 1 exact round
    gemm256<float><<<dim3(8, 32), 512, 0, stream>>>(aob, wobf, out, 8192, 1024, 1024);
}

// Round 4
// 142.977 us; speedup vs baseline: 1.1180x; 1.0289x over previous
//
#include <hip/hip_runtime.h>
#include <hip/hip_bf16.h>

// ---------------------------------------------------------------------------
// Sliding-window attention (B=4,S=2048,D=1024,H=16,HD=64,W=256) on gfx950.
// Pipeline: cvt(f32->bf16) -> GEMM(QKV, 256x192 8-phase) -> RoPE+reshape
//           (+permuted V^T) -> flash window attention -> GEMM(O-proj, 256x128).
// ---------------------------------------------------------------------------

typedef __bf16 bf16_t;
typedef __attribute__((ext_vector_type(8))) __bf16 bf16x8;
typedef __attribute__((ext_vector_type(4))) __bf16 bf16x4;
typedef __attribute__((ext_vector_type(4))) float f32x4;

#define MFMA16(a, b, c) __builtin_amdgcn_mfma_f32_16x16x32_bf16((a), (b), (c), 0, 0, 0)

// async global->LDS, 16 bytes per lane. LDS dest is wave-uniform base + lane*16.
__device__ __forceinline__ void async16(const void* g, void* l) {
    __builtin_amdgcn_global_load_lds(
        (const __attribute__((address_space(1))) unsigned int*)g,
        (__attribute__((address_space(3))) unsigned int*)l, 16, 0, 0);
}

#define BAR() do { asm volatile("" ::: "memory"); __builtin_amdgcn_s_barrier(); \
                   asm volatile("" ::: "memory"); } while (0)
#define VMC(N) asm volatile("s_waitcnt vmcnt(" #N ")" ::: "memory")

// ---------------------------------------------------------------------------
// f32 -> bf16 convert, 8 elems/thread
// ---------------------------------------------------------------------------
__global__ __launch_bounds__(256) void cvt_kernel(const float* __restrict__ s,
                                                  bf16_t* __restrict__ d, int n) {
    int i = (blockIdx.x * 256 + threadIdx.x) * 8;
    if (i >= n) return;
    float4 a = *(const float4*)(s + i);
    float4 b = *(const float4*)(s + i + 4);
    bf16x8 o;
    o[0] = (bf16_t)a.x; o[1] = (bf16_t)a.y; o[2] = (bf16_t)a.z; o[3] = (bf16_t)a.w;
    o[4] = (bf16_t)b.x; o[5] = (bf16_t)b.y; o[6] = (bf16_t)b.z; o[7] = (bf16_t)b.w;
    *(bf16x8*)(d + i) = o;
}

// ---------------------------------------------------------------------------
// 256x192 8-phase GEMM: C[M][N] = A[M][K] @ Bw[N][K]^T  (bf16 in, f32 acc).
// 512 threads = 8 waves (2M x 4N); per-wave C = 128x48 (acc = 96 regs).
// BK=64.  LDS 112 KiB: A = 2buf x 4units, B = 2buf x 3units; unit = 64 rows
// x 64 cols = 8 KiB, staged with ONE gload_lds per thread (512x16B), st_16x32
// XOR swizzle (byte ^= ((byte>>9)&1)<<5 within 1 KiB subtiles), linear LDS
// dest + inverse-swizzled global source + swizzled ds_read (both-sides rule).
//
// Iteration = 2 K-tiles (T even -> buf0, T+1 -> buf1), 8 phases x 12 MFMA.
// Cluster (mh,ks): 4mi x 3nj.  Every ds_read is FIRST-consumed by its own
// phase's MFMA (lgkm drained before the phase's trailing barrier), so the
// next phase may overwrite that LDS region.
//   P1 (T,0,ks0): rd afX(4)+bfX(3); stage A(T+1)u0,u1
//   P2 (T,1,ks0): rd afY(4);        stage A(T+1)u2,u3
//   P3 (T,0,ks1): rd afX(4)+bfY(3); -
//   P4 (T,1,ks1): rd afY(4);        stage B(T+2)u0;  VMC(1)  [certify T+1]
//   P5..P8: same on tile T+1 (buf1); stages: P5 B(T+2)u1,u2; P6 A(T+2)u0,u1;
//   P7 A(T+2)u2,u3; P8 B(T+3)u0,u1,u2; VMC(3)  [certify T+2]
// FIFO accounting (1 load/unit): @P4 outstanding = B(T+1)[3]+A(T+1)[4]+
// B(T+2)[1] = 8 -> VMC(1) drains exactly tile T+1's 7.  @P8 outstanding =
// B(T+2)[3]+A(T+2)[4]+B(T+3)[3] = 10 -> VMC(3) drains exactly tile T+2's 7.
// Race-freedom: region last-read phases: B(buf0)=P3, A(buf0)=P4,
// B(buf1)=P7, A(buf1)=P8; each overwriting stage issues >=1 barrier later.
// ---------------------------------------------------------------------------
template <typename OUT>
__global__ __launch_bounds__(512, 1) __attribute__((amdgpu_waves_per_eu(2)))
void gemm192(const bf16_t* __restrict__ A, const bf16_t* __restrict__ Bw,
             OUT* __restrict__ C, int M, int N, int K) {
    __shared__ __attribute__((aligned(16))) bf16_t As[32768];   // 2 x 4u x 8KiB
    __shared__ __attribute__((aligned(16))) bf16_t Bs[24576];   // 2 x 3u x 8KiB
    const int tid = threadIdx.x;
    const int l = tid & 63, w = tid >> 6;
    const int lr = l & 15, lg = l >> 4;
    const int wr = w >> 2, wc = w & 3;          // 2M x 4N

    const int nwg = gridDim.x * gridDim.y;
    const int flat = blockIdx.y * gridDim.x + blockIdx.x;
    const int swz = (flat & 7) * (nwg >> 3) + (flat >> 3);
    const int bx = swz % gridDim.x, by = swz / gridDim.x;
    const long m0 = (long)by * 256, n0 = (long)bx * 192;
    const int NT = K >> 6;       // 64-wide K tiles (even, >= 4)
    const int NI = NT >> 1;

    // staging decode (8 KiB unit = 64 rows x 64 cols, 1 load/thread):
    // linear LDS byte p -> unswizzle -> (row, col) -> global source.
    const int p  = w * 1024 + l * 16;
    const int pp = p ^ (((p >> 9) & 1) << 5);
    const int st = pp >> 10;                         // 1 KiB subtile 0..7
    const int rSt = (st >> 1) * 16 + ((pp >> 6) & 15);
    const int cSt = (st & 1) * 32 + ((pp >> 4) & 3) * 8;
    const bf16_t* aS = A  + (m0 + rSt) * K + cSt;
    const bf16_t* bS = Bw + (n0 + rSt) * K + cSt;
    const long uK = 64L * K;                         // unit row stride

    auto stageA = [&](int b, int u, int t) {
        async16(aS + (long)u * uK + (long)t * 64,
                (char*)As + b * 32768 + u * 8192 + w * 1024);
    };
    auto stageB = [&](int b, int u, int t) {
        async16(bS + (long)u * uK + (long)t * 64,
                (char*)Bs + b * 24576 + u * 8192 + w * 1024);
    };

    f32x4 acc[8][3] = {};
    bf16x8 afX[4], afY[4], bfX[3], bfY[3];
    const int swd = (lr & 8) << 2;    // ds_read swizzle: byte bit5 ^= row bit3

    auto loadAF = [&](int b, int mh, int ks, bf16x8 (&dst)[4]) {
#pragma unroll
        for (int mi = 0; mi < 4; ++mi) {
            const int off = (wr * 2 + mh) * 8192 + (mi * 2 + ks) * 1024 +
                            lr * 64 + lg * 16;
            dst[mi] = *(const bf16x8*)((const char*)As + b * 32768 + (off ^ swd));
        }
    };
    auto loadBF = [&](int b, int ks, bf16x8 (&dst)[3]) {
#pragma unroll
        for (int nj = 0; nj < 3; ++nj) {
            const int rg = wc * 48 + nj * 16 + lr;           // N-row 0..191
            const int off = (rg >> 6) * 8192 + (((rg >> 4) & 3) * 2 + ks) * 1024 +
                            lr * 64 + lg * 16;
            dst[nj] = *(const bf16x8*)((const char*)Bs + b * 24576 + (off ^ swd));
        }
    };

#define QMM(MH, AF, BF) do {                                                   \
    __builtin_amdgcn_s_setprio(1);                                             \
    _Pragma("unroll")                                                          \
    for (int mi = 0; mi < 4; ++mi)                                             \
        _Pragma("unroll")                                                      \
        for (int nj = 0; nj < 3; ++nj)                                         \
            acc[(MH)*4+mi][nj] = MFMA16((AF)[mi], (BF)[nj], acc[(MH)*4+mi][nj]); \
    __builtin_amdgcn_s_setprio(0);                                             \
} while (0)

    // ---- prologue: tile0 (A 4u + B 3u), then B(1) 3u; certify tile0 ----
    stageA(0, 0, 0); stageA(0, 1, 0); stageA(0, 2, 0); stageA(0, 3, 0);
    stageB(0, 0, 0); stageB(0, 1, 0); stageB(0, 2, 0);
    stageB(1, 0, 1); stageB(1, 1, 1); stageB(1, 2, 1);
    VMC(3);          // drain tile0's 7, keep B(1)'s 3
    BAR();

#pragma unroll 1
    for (int it = 0; it < NI - 1; ++it) {
        const int T = 2 * it;
        // P1 (tile T, mh0, ks0)
        loadAF(0, 0, 0, afX); loadBF(0, 0, bfX);
        stageA(1, 0, T + 1); stageA(1, 1, T + 1);
        BAR(); QMM(0, afX, bfX); BAR();
        // P2 (mh1, ks0)
        loadAF(0, 1, 0, afY);
        stageA(1, 2, T + 1); stageA(1, 3, T + 1);
        BAR(); QMM(1, afY, bfX); BAR();
        // P3 (mh0, ks1)
        loadAF(0, 0, 1, afX); loadBF(0, 1, bfY);
        BAR(); QMM(0, afX, bfY); BAR();
        // P4 (mh1, ks1): certify tile T+1
        loadAF(0, 1, 1, afY);
        stageB(0, 0, T + 2);
        BAR(); QMM(1, afY, bfY); VMC(1); BAR();
        // P5 (tile T+1, mh0, ks0)
        loadAF(1, 0, 0, afX); loadBF(1, 0, bfX);
        stageB(0, 1, T + 2); stageB(0, 2, T + 2);
        BAR(); QMM(0, afX, bfX); BAR();
        // P6 (mh1, ks0)
        loadAF(1, 1, 0, afY);
        stageA(0, 0, T + 2); stageA(0, 1, T + 2);
        BAR(); QMM(1, afY, bfX); BAR();
        // P7 (mh0, ks1)
        loadAF(1, 0, 1, afX); loadBF(1, 1, bfY);
        stageA(0, 2, T + 2); stageA(0, 3, T + 2);
        BAR(); QMM(0, afX, bfY); BAR();
        // P8 (mh1, ks1): certify tile T+2
        loadAF(1, 1, 1, afY);
        stageB(1, 0, T + 3); stageB(1, 1, T + 3); stageB(1, 2, T + 3);
        BAR(); QMM(1, afY, bfY); VMC(3); BAR();
    }

    // ---- final iteration (tiles NT-2 buf0, NT-1 buf1) ----
    {
        loadAF(0, 0, 0, afX); loadBF(0, 0, bfX);
        stageA(1, 0, NT - 1); stageA(1, 1, NT - 1);
        BAR(); QMM(0, afX, bfX); BAR();
        loadAF(0, 1, 0, afY);
        stageA(1, 2, NT - 1); stageA(1, 3, NT - 1);
        BAR(); QMM(1, afY, bfX); BAR();
        loadAF(0, 0, 1, afX); loadBF(0, 1, bfY);
        BAR(); QMM(0, afX, bfY); BAR();
        loadAF(0, 1, 1, afY);
        BAR(); QMM(1, afY, bfY);
        VMC(0); BAR();   // drain A(NT-1)[4] + B(NT-1)[3]
        // tile NT-1: fully resident, no LDS writers -> no barriers
        loadAF(1, 0, 0, afX); loadBF(1, 0, bfX);
        QMM(0, afX, bfX);
        loadAF(1, 1, 0, afY);
        QMM(1, afY, bfX);
        loadAF(1, 0, 1, afX); loadBF(1, 1, bfY);
        QMM(0, afX, bfY);
        loadAF(1, 1, 1, afY);
        QMM(1, afY, bfY);
    }
#undef QMM

    // ---- epilogue: fragment row = lg*4+j, col = lr ----
#pragma unroll
    for (int ai = 0; ai < 8; ++ai)
#pragma unroll
        for (int nj = 0; nj < 3; ++nj)
#pragma unroll
            for (int j = 0; j < 4; ++j) {
                long r = m0 + wr * 128 + ai * 16 + lg * 4 + j;
                long c = n0 + wc * 48 + nj * 16 + lr;
                C[r * (long)N + c] = (OUT)acc[ai][nj][j];
            }
}

// ---------------------------------------------------------------------------
// 256x128 GEMM (kept for O-proj: N=1024 -> 256 blocks = 1 exact round).
// Triple-buffered deep prefetch, counted vmcnt.  (See R3 notes.)
// ---------------------------------------------------------------------------
template <typename OUT>
__global__ __launch_bounds__(512, 2) void gemm256(const bf16_t* __restrict__ A,
                                                  const bf16_t* __restrict__ Bw,
                                                  OUT* __restrict__ C,
                                                  int M, int N, int K) {
    __shared__ __attribute__((aligned(16))) bf16_t As[49152];   // 3 x 2 x 128x64
    __shared__ __attribute__((aligned(16))) bf16_t Bs[24576];   // 3 x 128x64
    const int tid = threadIdx.x;
    const int l = tid & 63, w = tid >> 6;
    const int lr = l & 15, lg = l >> 4;
    const int wr = w >> 1, wc = w & 1;

    const int nwg = gridDim.x * gridDim.y;
    const int flat = blockIdx.y * gridDim.x + blockIdx.x;
    const int swz = (flat & 7) * (nwg >> 3) + (flat >> 3);
    const int bx = swz % gridDim.x, by = swz / gridDim.x;
    const long m0 = (long)by * 256, n0 = (long)bx * 128;
    const int NT = K >> 6;

    int rS[2], cS[2];
#pragma unroll
    for (int i = 0; i < 2; ++i) {
        const int p  = i * 8192 + w * 1024 + l * 16;
        const int pp = p ^ (((p >> 9) & 1) << 5);
        const int st = pp >> 10;
        rS[i] = (st >> 1) * 16 + ((pp >> 6) & 15);
        cS[i] = (st & 1) * 32 + ((pp >> 4) & 3) * 8;
    }
    const bf16_t* aSrc0 = A  + (m0 + rS[0]) * K + cS[0];
    const bf16_t* aSrc1 = A  + (m0 + rS[1]) * K + cS[1];
    const bf16_t* bSrc0 = Bw + (n0 + rS[0]) * K + cS[0];
    const bf16_t* bSrc1 = Bw + (n0 + rS[1]) * K + cS[1];
    const long hK = 128L * K;

    auto stageA = [&](int b, int h, int t) {
        char* d = (char*)As + b * 32768 + h * 16384 + w * 1024;
        const long o = (long)h * hK + (long)t * 64;
        async16(aSrc0 + o, d);
        async16(aSrc1 + o, d + 8192);
    };
    auto stageB = [&](int b, int t) {
        char* d = (char*)Bs + b * 16384 + w * 1024;
        const long o = (long)t * 64;
        async16(bSrc0 + o, d);
        async16(bSrc1 + o, d + 8192);
    };

    f32x4 acc[4][4] = {};
    bf16x8 af[4][2], blo[2][2], bhi[2][2];
    const int swd = (lr & 8) << 2;

    auto loadA = [&](int b) {
#pragma unroll
        for (int mi = 0; mi < 4; ++mi)
#pragma unroll
            for (int ks = 0; ks < 2; ++ks) {
                const int ra = (wr & 1) * 64 + mi * 16 + lr;
                const int off = ((ra >> 4) * 2 + ks) * 1024 + (ra & 15) * 64 + lg * 16;
                af[mi][ks] = *(const bf16x8*)((const char*)As + b * 32768 +
                                              (wr >> 1) * 16384 + (off ^ swd));
            }
    };
    auto loadB = [&](int b, int nh, bf16x8 (&dst)[2][2]) {
#pragma unroll
        for (int nj = 0; nj < 2; ++nj)
#pragma unroll
            for (int ks = 0; ks < 2; ++ks) {
                const int rb = wc * 64 + (nh * 2 + nj) * 16 + lr;
                const int off = ((rb >> 4) * 2 + ks) * 1024 + (rb & 15) * 64 + lg * 16;
                dst[nj][ks] = *(const bf16x8*)((const char*)Bs + b * 16384 +
                                               (off ^ swd));
            }
    };

#define QMM(NH, BF) do {                                                       \
    __builtin_amdgcn_s_setprio(1);                                             \
    _Pragma("unroll")                                                          \
    for (int mi = 0; mi < 4; ++mi) {                                           \
        acc[mi][(NH)*2]   = MFMA16(af[mi][0], (BF)[0][0], acc[mi][(NH)*2]);    \
        acc[mi][(NH)*2]   = MFMA16(af[mi][1], (BF)[0][1], acc[mi][(NH)*2]);    \
        acc[mi][(NH)*2+1] = MFMA16(af[mi][0], (BF)[1][0], acc[mi][(NH)*2+1]);  \
        acc[mi][(NH)*2+1] = MFMA16(af[mi][1], (BF)[1][1], acc[mi][(NH)*2+1]);  \
    }                                                                          \
    __builtin_amdgcn_s_setprio(0);                                             \
} while (0)

    stageA(0, 0, 0); stageA(0, 1, 0); stageB(0, 0);
    stageA(1, 0, 1); stageA(1, 1, 1); stageB(1, 1);
    VMC(6);
    BAR();

    int bc = 0;
#pragma unroll 1
    for (int t = 0; t < NT - 2; ++t) {
        const int bn = (bc + 2 >= 3) ? bc - 1 : bc + 2;
        loadA(bc); loadB(bc, 0, blo); stageA(bn, 0, t + 2); stageA(bn, 1, t + 2);
        BAR(); QMM(0, blo); BAR();
        loadB(bc, 1, bhi); stageB(bn, t + 2);
        BAR(); QMM(1, bhi);
        if (t < NT - 3) { VMC(6); } else { VMC(0); }
        BAR();
        bc = (bc + 1 >= 3) ? 0 : bc + 1;
    }
    {
        loadA(bc); loadB(bc, 0, blo);
        QMM(0, blo);
        loadB(bc, 1, bhi);
        QMM(1, bhi);
        const int b2 = (bc + 1 >= 3) ? 0 : bc + 1;
        loadA(b2); loadB(b2, 0, blo);
        QMM(0, blo);
        loadB(b2, 1, bhi);
        QMM(1, bhi);
    }
#undef QMM

#pragma unroll
    for (int mi = 0; mi < 4; ++mi)
#pragma unroll
        for (int ni = 0; ni < 4; ++ni)
#pragma unroll
            for (int j = 0; j < 4; ++j) {
                long r = m0 + wr * 64 + mi * 16 + lg * 4 + j;
                long c = n0 + wc * 64 + ni * 16 + lr;
                C[r * (long)N + c] = (OUT)acc[mi][ni][j];
            }
}

// ---------------------------------------------------------------------------
// RoPE + reshape. In: Cqkv[8192][3072] (q|k|v channel blocks), cos/sin[2048][32].
// Out: Q[bh][s][64], K[bh][s][64] (rope'd), VT[bh][64][2048] (transposed, with
// within-8-column permutation: position p holds key (p&~7)|rotl3(p&7) so the
// attention kernel's PV B-fragment needs NO cross-lane movement).
// ---------------------------------------------------------------------------
__global__ __launch_bounds__(256) void rope_reshape(const bf16_t* __restrict__ Cq,
                                                    const float* __restrict__ fcos,
                                                    const float* __restrict__ fsin,
                                                    bf16_t* __restrict__ Qo,
                                                    bf16_t* __restrict__ Ko,
                                                    bf16_t* __restrict__ VT) {
    __shared__ __attribute__((aligned(16))) bf16_t vt[64][72];
    const int blk = blockIdx.x;
    const int st = blk & 31, bh = blk >> 5;
    const int h = bh & 15, b = bh >> 4;
    const int s0 = st << 6;
    const int tid = threadIdx.x;
    const int i = tid >> 2, dq = (tid & 3) << 4;
    const int s = s0 + i;

    const bf16_t* base = Cq + (long)(b * 2048 + s) * 3072 + h * 64 + dq;
    bf16x8 q0v = *(const bf16x8*)(base);
    bf16x8 q1v = *(const bf16x8*)(base + 8);
    bf16x8 k0v = *(const bf16x8*)(base + 1024);
    bf16x8 k1v = *(const bf16x8*)(base + 1032);
    bf16x8 v0v = *(const bf16x8*)(base + 2048);
    bf16x8 v1v = *(const bf16x8*)(base + 2056);

    float cs[8], sn[8];
    {
        const float* cp = fcos + (long)s * 32 + (dq >> 1);
        const float* sp = fsin + (long)s * 32 + (dq >> 1);
        float4 a = *(const float4*)cp, b2 = *(const float4*)(cp + 4);
        float4 c = *(const float4*)sp, d2 = *(const float4*)(sp + 4);
        cs[0]=a.x; cs[1]=a.y; cs[2]=a.z; cs[3]=a.w; cs[4]=b2.x; cs[5]=b2.y; cs[6]=b2.z; cs[7]=b2.w;
        sn[0]=c.x; sn[1]=c.y; sn[2]=c.z; sn[3]=c.w; sn[4]=d2.x; sn[5]=d2.y; sn[6]=d2.z; sn[7]=d2.w;
    }

    auto rope8 = [&](bf16x8 v, int fo) -> bf16x8 {
        bf16x8 o;
#pragma unroll
        for (int p = 0; p < 4; ++p) {
            float v0 = (float)v[2 * p], v1 = (float)v[2 * p + 1];
            float c = cs[fo + p], s2 = sn[fo + p];
            o[2 * p]     = (bf16_t)(v0 * c - v1 * s2);
            o[2 * p + 1] = (bf16_t)(v0 * s2 + v1 * c);
        }
        return o;
    };

    bf16x8 qo0 = rope8(q0v, 0), qo1 = rope8(q1v, 4);
    bf16x8 ko0 = rope8(k0v, 0), ko1 = rope8(k1v, 4);

    const long qaddr = ((long)bh * 2048 + s) * 64 + dq;
    *(bf16x8*)(Qo + qaddr) = qo0;
    *(bf16x8*)(Qo + qaddr + 8) = qo1;
    *(bf16x8*)(Ko + qaddr) = ko0;
    *(bf16x8*)(Ko + qaddr + 8) = ko1;

    *(bf16x8*)&vt[i][dq] = v0v;
    *(bf16x8*)&vt[i][dq + 8] = v1v;
    __syncthreads();
    const int d = tid >> 2, sb = (tid & 3) << 4;
    bf16x8 o0, o1;
#pragma unroll
    for (int j = 0; j < 8; ++j) {
        const int f = ((j & 3) << 1) | ((j >> 2) & 1);
        o0[j] = vt[sb + f][d];
        o1[j] = vt[sb + 8 + f][d];
    }
    const long va = ((long)bh * 64 + d) * 2048 + s0 + sb;
    *(bf16x8*)(VT + va) = o0;
    *(bf16x8*)(VT + va + 8) = o1;
}

// ---------------------------------------------------------------------------
// Sliding-window attention v4: whole K/V window staged to LDS up front,
// online softmax per 64-key tile, swapped QK^T, P packs directly into the
// PV B-fragment (V^T stored with within-8 key permutation by rope_reshape).
// ---------------------------------------------------------------------------
__global__ __launch_bounds__(256, 2) void attn_win4(const bf16_t* __restrict__ Q,
                                                    const bf16_t* __restrict__ Kb,
                                                    const bf16_t* __restrict__ VT,
                                                    bf16_t* __restrict__ Ao) {
    __shared__ __attribute__((aligned(16))) bf16_t kld[5 * 4096];
    __shared__ __attribute__((aligned(16))) bf16_t vld[5 * 4096];
    const int raw = blockIdx.x;
    const int mswz = ((raw & 7) << 8) | (raw >> 3);
    const int qt = mswz & 31, bh = mswz >> 5;
    const int h = bh & 15, b = bh >> 4;
    const int l = threadIdx.x & 63, w = threadIdx.x >> 6;
    const int lr = l & 15, lg = l >> 4;
    const int q0 = qt * 64 + w * 16;
    const int q = q0 + lr;
    const int tb = qt - 4;

    const bf16_t* Qp = Q + (long)bh * 2048 * 64;
    const bf16_t* Kp = Kb + (long)bh * 2048 * 64;
    const bf16_t* Vp = VT + (long)bh * 64 * 2048;

#pragma unroll
    for (int u = 0; u < 5; ++u) {
        const int kt = tb + u;
        const int kt64 = (kt < 0 ? 0 : kt) * 64;
#pragma unroll
        for (int part = 0; part < 2; ++part) {
            const int seg = w * 2 + part;
            const int r = seg * 8 + (l >> 3);
            const int sc = (l & 7) ^ ((r >> 1) & 7);
            async16(Kp + (long)(kt64 + r) * 64 + sc * 8,
                    (char*)kld + u * 8192 + seg * 1024);
            async16(Vp + (long)r * 2048 + kt64 + sc * 8,
                    (char*)vld + u * 8192 + seg * 1024);
        }
    }

    const bf16x8 qb0 = *(const bf16x8*)&Qp[q * 64 + lg * 8];
    const bf16x8 qb1 = *(const bf16x8*)&Qp[q * 64 + 32 + lg * 8];

    __syncthreads();

    float mrun = -1000.f, lsum = 0.f;
    f32x4 o0 = {0.f, 0.f, 0.f, 0.f}, o1 = {0.f, 0.f, 0.f, 0.f};
    f32x4 o2 = {0.f, 0.f, 0.f, 0.f}, o3 = {0.f, 0.f, 0.f, 0.f};
    const int swv = (lr >> 1) & 7;

#define QKF(DST, HH, MM)                                                         \
    f32x4 DST; {                                                                 \
        const int row_ = (HH) * 32 + 2 * lr + (MM);                              \
        const int sw_ = (row_ >> 1) & 7;                                         \
        bf16x8 k0_ = *(const bf16x8*)(kbase + row_ * 128 + ((lg ^ sw_) << 4));   \
        bf16x8 k1_ = *(const bf16x8*)(kbase + row_ * 128 + (((4 + lg) ^ sw_) << 4)); \
        f32x4 s_ = {0.f, 0.f, 0.f, 0.f};                                         \
        s_ = MFMA16(k0_, qb0, s_);                                               \
        s_ = MFMA16(k1_, qb1, s_);                                               \
        const int kb_ = k0s + (HH) * 32 + (MM) + lg * 8;                         \
        DST[0] = ((kb_ >= 0) & ((unsigned)(q - kb_) < 256u))         ? s_[0] * 0.125f : -1e30f; \
        DST[1] = ((kb_ + 2 >= 0) & ((unsigned)(q - kb_ - 2) < 256u)) ? s_[1] * 0.125f : -1e30f; \
        DST[2] = ((kb_ + 4 >= 0) & ((unsigned)(q - kb_ - 4) < 256u)) ? s_[2] * 0.125f : -1e30f; \
        DST[3] = ((kb_ + 6 >= 0) & ((unsigned)(q - kb_ - 6) < 256u)) ? s_[3] * 0.125f : -1e30f; \
    }

#define EXV(S_) {                                                                \
        S_[0] = __expf(S_[0] - mnew); S_[1] = __expf(S_[1] - mnew);              \
        S_[2] = __expf(S_[2] - mnew); S_[3] = __expf(S_[3] - mnew);              \
        rs += (S_[0] + S_[1]) + (S_[2] + S_[3]); }

#define PVF(NT, HH, PB) {                                                        \
        bf16x8 va_ = *(const bf16x8*)(vbase + ((NT) * 16 + lr) * 128 +           \
                                      ((((HH) * 4 + lg) ^ swv) << 4));           \
        o##NT = MFMA16(va_, PB, o##NT); }

#pragma unroll
    for (int u = 0; u < 5; ++u) {
        const char* kbase = (const char*)kld + u * 8192;
        const char* vbase = (const char*)vld + u * 8192;
        const int k0s = (tb + u) * 64;

        QKF(sA, 0, 0) QKF(sB, 0, 1) QKF(sC, 1, 0) QKF(sD, 1, 1)

        float tm = fmaxf(fmaxf(fmaxf(sA[0], sA[1]), fmaxf(sA[2], sA[3])),
                         fmaxf(fmaxf(sB[0], sB[1]), fmaxf(sB[2], sB[3])));
        tm = fmaxf(tm, fmaxf(fmaxf(fmaxf(sC[0], sC[1]), fmaxf(sC[2], sC[3])),
                             fmaxf(fmaxf(sD[0], sD[1]), fmaxf(sD[2], sD[3]))));
        tm = fmaxf(tm, __shfl_xor(tm, 16));
        tm = fmaxf(tm, __shfl_xor(tm, 32));
        const float mnew = fmaxf(mrun, tm);
        const float alpha = __expf(mrun - mnew);
        mrun = mnew;

        float rs = 0.f;
        EXV(sA) EXV(sB) EXV(sC) EXV(sD)
        rs += __shfl_xor(rs, 16);
        rs += __shfl_xor(rs, 32);
        lsum = lsum * alpha + rs;

        o0[0] *= alpha; o0[1] *= alpha; o0[2] *= alpha; o0[3] *= alpha;
        o1[0] *= alpha; o1[1] *= alpha; o1[2] *= alpha; o1[3] *= alpha;
        o2[0] *= alpha; o2[1] *= alpha; o2[2] *= alpha; o2[3] *= alpha;
        o3[0] *= alpha; o3[1] *= alpha; o3[2] *= alpha; o3[3] *= alpha;

        bf16x8 pb0, pb1;
        pb0[0] = (bf16_t)sA[0]; pb0[1] = (bf16_t)sA[1]; pb0[2] = (bf16_t)sA[2]; pb0[3] = (bf16_t)sA[3];
        pb0[4] = (bf16_t)sB[0]; pb0[5] = (bf16_t)sB[1]; pb0[6] = (bf16_t)sB[2]; pb0[7] = (bf16_t)sB[3];
        pb1[0] = (bf16_t)sC[0]; pb1[1] = (bf16_t)sC[1]; pb1[2] = (bf16_t)sC[2]; pb1[3] = (bf16_t)sC[3];
        pb1[4] = (bf16_t)sD[0]; pb1[5] = (bf16_t)sD[1]; pb1[6] = (bf16_t)sD[2]; pb1[7] = (bf16_t)sD[3];

        PVF(0, 0, pb0) PVF(1, 0, pb0) PVF(2, 0, pb0) PVF(3, 0, pb0)
        PVF(0, 1, pb1) PVF(1, 1, pb1) PVF(2, 1, pb1) PVF(3, 1, pb1)
    }
#undef QKF
#undef EXV
#undef PVF

    const float rinv = 1.0f / lsum;
    bf16_t* aor = Ao + ((long)(b * 2048) + q) * 1024 + h * 64;
#define EPI(NT, OA_) {                                                           \
        bf16x4 ov_;                                                             \
        ov_[0] = (bf16_t)(OA_[0] * rinv); ov_[1] = (bf16_t)(OA_[1] * rinv);      \
        ov_[2] = (bf16_t)(OA_[2] * rinv); ov_[3] = (bf16_t)(OA_[3] * rinv);      \
        *(bf16x4*)(aor + (NT) * 16 + lg * 4) = ov_; }
    EPI(0, o0) EPI(1, o1) EPI(2, o2) EPI(3, o3)
#undef EPI
}

// ---------------------------------------------------------------------------
extern "C" void kernel_launch(void* const* d_in, const int* in_sizes, int n_in,
                              void* d_out, int out_size, void* d_ws, size_t ws_size,
                              hipStream_t stream) {
    (void)in_sizes; (void)n_in; (void)out_size; (void)ws_size;
    const float* x    = (const float*)d_in[0];
    const float* fcos = (const float*)d_in[1];
    const float* fsin = (const float*)d_in[2];
    const float* wq   = (const float*)d_in[3];
    const float* wk   = (const float*)d_in[4];
    const float* wv   = (const float*)d_in[5];
    const float* wo   = (const float*)d_in[6];
    float* out = (float*)d_out;

    char* ws = (char*)d_ws;
    // layout (bytes): xbf 16MB | wqkv 6MB | wobf 2MB | qkvc 48MB | k 16MB | vt 16MB
    bf16_t* xbf  = (bf16_t*)(ws);
    bf16_t* wqkv = (bf16_t*)(ws + 16777216);
    bf16_t* wobf = (bf16_t*)(ws + 23068672);
    bf16_t* qkvc = (bf16_t*)(ws + 25165824);
    bf16_t* kbuf = (bf16_t*)(ws + 75497472);
    bf16_t* vtb  = (bf16_t*)(ws + 92274688);
    bf16_t* qbuf = xbf;   // xbf dead after GEMM1
    bf16_t* aob  = qkvc;  // qkvc dead after rope

    cvt_kernel<<<4096, 256, 0, stream>>>(x, xbf, 8388608);
    cvt_kernel<<<512, 256, 0, stream>>>(wq, wqkv, 1048576);
    cvt_kernel<<<512, 256, 0, stream>>>(wk, wqkv + 1048576, 1048576);
    cvt_kernel<<<512, 256, 0, stream>>>(wv, wqkv + 2097152, 1048576);
    cvt_kernel<<<512, 256, 0, stream>>>(wo, wobf, 1048576);

    // QKV: grid (N/192, M/256) = (16, 32) = 512 blocks = 2 exact rounds
    gemm192<bf16_t><<<dim3(16, 32), 512, 0, stream>>>(xbf, wqkv, qkvc, 8192, 3072, 1024);
    rope_reshape<<<2048, 256, 0, stream>>>(qkvc, fcos, fsin, qbuf, kbuf, vtb);
    attn_win4<<<2048, 256, 0, stream>>>(qbuf, kbuf, vtb, aob);
    // O-proj: grid (8, 32) = 256 blocks = 1 exact round
    gemm256<float><<<dim3(8, 32), 512, 0, stream>>>(aob, wobf, out, 8192, 1024, 1024);
}